// Round 1
// baseline (2858.714 us; speedup 1.0000x reference)
//
#include <hip/hip_runtime.h>
#include <math.h>

#define HS 524288
#define HSM (HS - 1)
#define ENC_NEGINF 0x007FFFFFu

__device__ __forceinline__ unsigned encf(float f) {
    unsigned b = __float_as_uint(f);
    return (b & 0x80000000u) ? ~b : (b | 0x80000000u);
}
__device__ __forceinline__ float decf(unsigned u) {
    return __uint_as_float((u & 0x80000000u) ? (u & 0x7FFFFFFFu) : ~u);
}

__device__ __forceinline__ unsigned short f2bf(float x) {
    unsigned u = __float_as_uint(x);
    unsigned r = u + 0x7FFFu + ((u >> 16) & 1u);
    return (unsigned short)(r >> 16);
}
__device__ __forceinline__ float bf2f(unsigned short h) {
    return __uint_as_float(((unsigned)h) << 16);
}

// ---------------------------------------------------------------- setup kernels

__global__ __launch_bounds__(256) void k_init_static(unsigned* hashK, int* hashV,
                                                     int* rowcnt, int* colcnt, int N) {
    int i = blockIdx.x * 256 + threadIdx.x;
    if (i < HS) { hashK[i] = 0xFFFFFFFFu; hashV[i] = 0x7FFFFFFF; }
    if (i < N) { rowcnt[i] = 0; colcnt[i] = 0; }
}

__global__ __launch_bounds__(256) void k_hash_insert(const int* __restrict__ row,
                                                     const int* __restrict__ col,
                                                     unsigned* hashK, int* hashV, int N, int E) {
    int e = blockIdx.x * 256 + threadIdx.x;
    if (e >= E) return;
    unsigned key = (unsigned)row[e] * (unsigned)N + (unsigned)col[e];
    unsigned h = (key * 2654435761u) >> 13; h &= HSM;
    while (true) {
        unsigned prev = atomicCAS(&hashK[h], 0xFFFFFFFFu, key);
        if (prev == 0xFFFFFFFFu || prev == key) { atomicMin(&hashV[h], e); break; }
        h = (h + 1) & HSM;
    }
}

__global__ __launch_bounds__(256) void k_hash_lookup(const int* __restrict__ row,
                                                     const int* __restrict__ col,
                                                     const unsigned* __restrict__ hashK,
                                                     const int* __restrict__ hashV,
                                                     int* __restrict__ ridx,
                                                     int* rowcnt, int* colcnt, int N, int E) {
    int e = blockIdx.x * 256 + threadIdx.x;
    if (e >= E) return;
    int r = row[e], c = col[e];
    unsigned rkey = (unsigned)c * (unsigned)N + (unsigned)r;
    unsigned h = (rkey * 2654435761u) >> 13; h &= HSM;
    int res = -1;
    while (true) {
        unsigned kk = hashK[h];
        if (kk == rkey) { res = hashV[h]; break; }
        if (kk == 0xFFFFFFFFu) break;
        h = (h + 1) & HSM;
    }
    ridx[e] = res;
    atomicAdd(&rowcnt[r], 1);
    atomicAdd(&colcnt[c], 1);
}

__global__ __launch_bounds__(256) void k_layer_init(unsigned* aggenc, float* outf, float* incf, int NC) {
    int i = blockIdx.x * 256 + threadIdx.x;
    if (i >= NC) return;
    aggenc[i] = ENC_NEGINF;
    outf[i] = 0.f;
    incf[i] = 0.f;
}

// Weight prep: src fp32 [K][Nn] row-major -> whi/wlo bf16 [Nn][K] (transposed + split)
__global__ __launch_bounds__(256) void k_prep_wt(const float* __restrict__ src,
                                                 unsigned short* __restrict__ whi,
                                                 unsigned short* __restrict__ wlo,
                                                 int K, int Nn) {
    int idx = blockIdx.x * 256 + threadIdx.x;
    if (idx >= K * Nn) return;
    int k = idx / Nn, n = idx - k * Nn;
    float v = src[idx];
    unsigned short h = f2bf(v);
    float hf = bf2f(h);
    unsigned short l = f2bf(v - hf);
    whi[(size_t)n * K + k] = h;
    wlo[(size_t)n * K + k] = l;
}

// ---------------------------------------------------------------- generic fp32 GEMM (node-side)
template <int ACT>
__global__ __launch_bounds__(256) void k_gemm(const float* __restrict__ A,
                                              const float* __restrict__ B,
                                              const float* __restrict__ bias,
                                              float* __restrict__ C,
                                              int M, int Nd, int K, int lda, int ldb, int ldc) {
    __shared__ float As[16][64];
    __shared__ float Bs[16][64];
    const int tid = threadIdx.x;
    const int bm = blockIdx.y * 64, bn = blockIdx.x * 64;
    const int tx = tid & 15, ty = tid >> 4;
    const int mload = tid >> 2, k4 = (tid & 3) << 2;
    const int kload = tid >> 4, n4 = (tid & 15) << 2;
    float acc[4][4] = {};
    const int gmload = bm + mload;
    const bool avalid = (gmload < M);
    const float* aptr = A + (size_t)(avalid ? gmload : (M - 1)) * lda + k4;
    const float* bptr = B + (size_t)kload * ldb + bn + n4;
    for (int kb = 0; kb < K; kb += 16) {
        float4 av = avalid ? *(const float4*)(aptr + kb) : make_float4(0.f, 0.f, 0.f, 0.f);
        As[k4 + 0][mload] = av.x; As[k4 + 1][mload] = av.y;
        As[k4 + 2][mload] = av.z; As[k4 + 3][mload] = av.w;
        *(float4*)&Bs[kload][n4] = *(const float4*)(bptr + (size_t)kb * ldb);
        __syncthreads();
#pragma unroll
        for (int k = 0; k < 16; ++k) {
            float4 a = *(const float4*)&As[k][ty << 2];
            float4 b = *(const float4*)&Bs[k][tx << 2];
            acc[0][0] += a.x * b.x; acc[0][1] += a.x * b.y; acc[0][2] += a.x * b.z; acc[0][3] += a.x * b.w;
            acc[1][0] += a.y * b.x; acc[1][1] += a.y * b.y; acc[1][2] += a.y * b.z; acc[1][3] += a.y * b.w;
            acc[2][0] += a.z * b.x; acc[2][1] += a.z * b.y; acc[2][2] += a.z * b.z; acc[2][3] += a.z * b.w;
            acc[3][0] += a.w * b.x; acc[3][1] += a.w * b.y; acc[3][2] += a.w * b.z; acc[3][3] += a.w * b.w;
        }
        __syncthreads();
    }
#pragma unroll
    for (int i = 0; i < 4; ++i) {
        int gm = bm + (ty << 2) + i;
        if (gm >= M) continue;
        float* crow = C + (size_t)gm * ldc;
#pragma unroll
        for (int j = 0; j < 4; ++j) {
            int gn = bn + (tx << 2) + j;
            float v = acc[i][j];
            if (bias) v += bias[gn];
            if (ACT == 1) v = fmaxf(v, 0.f);
            if (ACT == 2) v = 1.f / (1.f + __expf(-v));
            crow[gn] = v;
        }
    }
}

// ---------------------------------------------------------------- MFMA split-bf16 GEMM
// 128x128 tile, BK=32, 4 waves (2x2), each wave 64x64 via 16x16x32 bf16 MFMA.
// 3-term split: D += Ahi*Bhi + Alo*Bhi + Ahi*Blo  (error ~2^-17, fp32-equivalent).
// A is fp32 in memory, split on the fly during LDS staging. B is pre-split bf16 [N][K].
// MODE 0 (H1): A = [ef[e] | ef[ridx[e]]], K=256, epilogue relu(acc+eB1+xa[row]+xb[col]) -> h1c
// MODE 1 (U):  A = h1c, K=384, epilogue acc+eB2 -> atomics outf/incf + store (relu or raw)
// MODE 2 (K):  A = ef, K=128, epilogue acc+kB -> kbuf

#define LDP 40   // LDS row pitch in shorts (BK 32 + 8): 80B rows, 16B-aligned, ~2-way banks

using bfrag = __attribute__((ext_vector_type(8))) short;
using ffrag = __attribute__((ext_vector_type(4))) float;

template <int MODE, int KSTEPS>
__global__ __launch_bounds__(256) void k_mfma_gemm(const float* __restrict__ Asrc,
                                                   const int* __restrict__ ridx,
                                                   const unsigned short* __restrict__ Bhi,
                                                   const unsigned short* __restrict__ Blo,
                                                   const float* __restrict__ bias,
                                                   const float* __restrict__ xa,
                                                   const float* __restrict__ xb,
                                                   const int* __restrict__ rowArr,
                                                   const int* __restrict__ colArr,
                                                   float* __restrict__ outC,
                                                   float* __restrict__ outf,
                                                   float* __restrict__ incf,
                                                   int edgeBase, int Mrows, int reluOut) {
    constexpr int K = KSTEPS * 32;
    __shared__ unsigned short Ah[128 * LDP];
    __shared__ unsigned short Al[128 * LDP];
    __shared__ unsigned short Bh[128 * LDP];
    __shared__ unsigned short Bl[128 * LDP];

    const int tid = threadIdx.x;
    const int bm = blockIdx.y * 128;
    const int bx = blockIdx.x;

    // staging assignment: thread -> row r = tid>>1, k-half kh = (tid&1)*16
    const int sr = tid >> 1;
    const int kh = (tid & 1) * 16;

    // A row pointers
    const float* p0;
    const float* p1 = nullptr;
    {
        int rc = min(bm + sr, Mrows - 1);
        if (MODE == 0) {
            int e = edgeBase + rc;
            p0 = Asrc + (size_t)e * 128;
            int rv = ridx[e];
            p1 = (rv >= 0) ? (Asrc + (size_t)rv * 128) : nullptr;
        } else if (MODE == 1) {
            p0 = Asrc + (size_t)rc * 384;
        } else {
            p0 = Asrc + (size_t)rc * 128;
        }
    }
    // B row pointers
    const unsigned short* bhp = Bhi + (size_t)(bx * 128 + sr) * K + kh;
    const unsigned short* blp = Blo + (size_t)(bx * 128 + sr) * K + kh;

    const int wid = tid >> 6;
    const int lane = tid & 63;
    const int wr0 = (wid >> 1) * 64;
    const int wc0 = (wid & 1) * 64;
    const int lm = lane & 15;
    const int lk = (lane >> 4) * 8;

    ffrag acc[4][4];
#pragma unroll
    for (int i = 0; i < 4; ++i)
#pragma unroll
        for (int j = 0; j < 4; ++j)
            acc[i][j] = (ffrag){0.f, 0.f, 0.f, 0.f};

    unsigned short* AhW = &Ah[sr * LDP + kh];
    unsigned short* AlW = &Al[sr * LDP + kh];
    unsigned short* BhW = &Bh[sr * LDP + kh];
    unsigned short* BlW = &Bl[sr * LDP + kh];

    for (int ks = 0; ks < KSTEPS; ++ks) {
        const int kb = ks * 32;
        // ---- stage A (fp32 -> split bf16)
        const float* ap;
        if (MODE == 0) ap = (kb < 128) ? (p0 + kb) : (p1 ? p1 + (kb - 128) : nullptr);
        else ap = p0 + kb;
#pragma unroll
        for (int c = 0; c < 4; ++c) {
            float4 f = ap ? *(const float4*)(ap + kh + c * 4) : make_float4(0.f, 0.f, 0.f, 0.f);
            ushort4 h, l;
            h.x = f2bf(f.x); l.x = f2bf(f.x - bf2f(h.x));
            h.y = f2bf(f.y); l.y = f2bf(f.y - bf2f(h.y));
            h.z = f2bf(f.z); l.z = f2bf(f.z - bf2f(h.z));
            h.w = f2bf(f.w); l.w = f2bf(f.w - bf2f(h.w));
            *(ushort4*)(AhW + c * 4) = h;
            *(ushort4*)(AlW + c * 4) = l;
        }
        // ---- stage B (pre-split bf16, straight copy)
        {
            uint4 b0 = *(const uint4*)(bhp + kb);
            uint4 b1 = *(const uint4*)(bhp + kb + 8);
            uint4 c0 = *(const uint4*)(blp + kb);
            uint4 c1 = *(const uint4*)(blp + kb + 8);
            *(uint4*)(BhW) = b0; *(uint4*)(BhW + 8) = b1;
            *(uint4*)(BlW) = c0; *(uint4*)(BlW + 8) = c1;
        }
        __syncthreads();
        // ---- fragments + MFMA
        bfrag a_h[4], a_l[4], b_h[4], b_l[4];
#pragma unroll
        for (int mt = 0; mt < 4; ++mt) {
            int base = (wr0 + mt * 16 + lm) * LDP + lk;
            a_h[mt] = *(const bfrag*)&Ah[base];
            a_l[mt] = *(const bfrag*)&Al[base];
        }
#pragma unroll
        for (int nt = 0; nt < 4; ++nt) {
            int base = (wc0 + nt * 16 + lm) * LDP + lk;
            b_h[nt] = *(const bfrag*)&Bh[base];
            b_l[nt] = *(const bfrag*)&Bl[base];
        }
#pragma unroll
        for (int mt = 0; mt < 4; ++mt)
#pragma unroll
            for (int nt = 0; nt < 4; ++nt) {
                acc[mt][nt] = __builtin_amdgcn_mfma_f32_16x16x32_bf16(a_h[mt], b_h[nt], acc[mt][nt], 0, 0, 0);
                acc[mt][nt] = __builtin_amdgcn_mfma_f32_16x16x32_bf16(a_l[mt], b_h[nt], acc[mt][nt], 0, 0, 0);
                acc[mt][nt] = __builtin_amdgcn_mfma_f32_16x16x32_bf16(a_h[mt], b_l[nt], acc[mt][nt], 0, 0, 0);
            }
        __syncthreads();
    }

    // ---- epilogue. C/D layout: col = lane&15, row = (lane>>4)*4 + reg.
    float bv[4];
#pragma unroll
    for (int nt = 0; nt < 4; ++nt) bv[nt] = bias[bx * 128 + wc0 + nt * 16 + lm];

#pragma unroll
    for (int mt = 0; mt < 4; ++mt) {
#pragma unroll
        for (int i = 0; i < 4; ++i) {
            int grow = bm + wr0 + mt * 16 + (lane >> 4) * 4 + i;
            if (grow >= Mrows) continue;
            if (MODE == 0) {
                int e = edgeBase + grow;
                size_t re = (size_t)rowArr[e] * 384;
                size_t ce = (size_t)colArr[e] * 384;
                float* crow = outC + (size_t)grow * 384;
#pragma unroll
                for (int nt = 0; nt < 4; ++nt) {
                    int gcol = bx * 128 + wc0 + nt * 16 + lm;
                    float v = acc[mt][nt][i] + bv[nt] + xa[re + gcol] + xb[ce + gcol];
                    crow[gcol] = fmaxf(v, 0.f);
                }
            } else if (MODE == 1) {
                int e = edgeBase + grow;
                size_t re = (size_t)rowArr[e] * 128;
                size_t ce = (size_t)colArr[e] * 128;
                float* crow = outC + (size_t)e * 128;
#pragma unroll
                for (int nt = 0; nt < 4; ++nt) {
                    int gcol = wc0 + nt * 16 + lm;
                    float v = acc[mt][nt][i] + bv[nt];
                    atomicAdd(&outf[re + gcol], v);
                    atomicAdd(&incf[ce + gcol], v);
                    crow[gcol] = reluOut ? fmaxf(v, 0.f) : v;
                }
            } else {
                float* crow = outC + (size_t)grow * 128;
#pragma unroll
                for (int nt = 0; nt < 4; ++nt) {
                    int gcol = wc0 + nt * 16 + lm;
                    crow[gcol] = acc[mt][nt][i] + bv[nt];
                }
            }
        }
    }
}

// ---------------------------------------------------------------- distance-gate MLP precompute
// dm[e] = sigmoid( relu(dfeat @ dW1 + dB1) @ dW2 + dB2 ), dfeat = [dx,dy,dz,dist]
// One thread per edge; weights staged in LDS (broadcast reads).

__global__ __launch_bounds__(256) void k_dm(const float* __restrict__ desc,
                                            const int* __restrict__ row,
                                            const int* __restrict__ col,
                                            const float* __restrict__ dW1,
                                            const float* __restrict__ dB1,
                                            const float* __restrict__ dW2,
                                            const float* __restrict__ dB2,
                                            float* __restrict__ dmbuf, int E) {
    __shared__ float sw[128];
    __shared__ float sb[32];
    __shared__ float sv[32];
    for (int i = threadIdx.x; i < 128; i += 256) sw[i] = dW1[i];
    if (threadIdx.x < 32) { sb[threadIdx.x] = dB1[threadIdx.x]; sv[threadIdx.x] = dW2[threadIdx.x]; }
    __syncthreads();
    const float db2v = dB2[0];
    for (int e = blockIdx.x * 256 + threadIdx.x; e < E; e += gridDim.x * 256) {
        int r = row[e], c = col[e];
        float dx = desc[r * 8 + 0] - desc[c * 8 + 0];
        float dy = desc[r * 8 + 1] - desc[c * 8 + 1];
        float dz = desc[r * 8 + 2] - desc[c * 8 + 2];
        float dist = sqrtf(dx * dx + dy * dy + dz * dz);
        float acc = db2v;
#pragma unroll
        for (int j = 0; j < 32; ++j) {
            float t = sb[j] + dx * sw[j] + dy * sw[32 + j] + dz * sw[64 + j] + dist * sw[96 + j];
            acc += fmaxf(t, 0.f) * sv[j];
        }
        dmbuf[e] = 1.f / (1.f + __expf(-acc));
    }
}

// ---------------------------------------------------------------- attention kernel
// One (edge, head) pair per LANE: wave = 8 edges x 8 heads. All matvecs are
// register-resident FMA loops over broadcast float4 LDS weight reads; softmax
// over the 16 logits is entirely lane-local. No shuffles, no wave barriers.

__global__ __launch_bounds__(256) void k_attn(const float* __restrict__ xq,
                                              const float* __restrict__ kbuf,
                                              const float* __restrict__ xv,
                                              const int* __restrict__ row,
                                              const int* __restrict__ col,
                                              const float* __restrict__ attW1,
                                              const float* __restrict__ attB1,
                                              const float* __restrict__ attW2,
                                              const float* __restrict__ attB2,
                                              const float* __restrict__ dmbuf,
                                              float* __restrict__ prob_out,
                                              unsigned* __restrict__ aggenc, int E) {
    __shared__ float sW1[1024];   // [o][c] 32x32
    __shared__ float sW2[512];    // [o2][c] 16x32
    __shared__ float sB1[32];
    __shared__ float sB2[16];
    for (int i = threadIdx.x; i < 1024; i += 256) sW1[i] = attW1[i];
    for (int i = threadIdx.x; i < 512; i += 256) sW2[i] = attW2[i];
    if (threadIdx.x < 32) sB1[threadIdx.x] = attB1[threadIdx.x];
    if (threadIdx.x < 16) sB2[threadIdx.x] = attB2[threadIdx.x];
    __syncthreads();

    const int lane = threadIdx.x & 63;
    const int le = lane >> 3;   // edge slot within wave
    const int hd = lane & 7;    // head
    const int gwave = (blockIdx.x * 256 + threadIdx.x) >> 6;
    const int nw = (gridDim.x * 256) >> 6;
    const int ngrp = (E + 7) >> 3;

    for (int g = gwave; g < ngrp; g += nw) {
        const int e = g * 8 + le;
        const bool valid = (e < E);
        const int ec = valid ? e : (E - 1);
        const int r = row[ec], cl = col[ec];
        const float dm = dmbuf[ec];

        // gather h = [q(16) | k(16)] for this (edge, head): stride-8 dword reads
        float h[32];
        const float* qp = xq + (size_t)r * 128 + hd;
        const float* kp = kbuf + (size_t)ec * 128 + hd;
#pragma unroll
        for (int ci = 0; ci < 16; ++ci) h[ci] = qp[ci * 8];
#pragma unroll
        for (int ci = 0; ci < 16; ++ci) h[16 + ci] = kp[ci * 8];

        // h1 = relu(W1 @ h + b1)   (32x32 matvec, broadcast weight reads)
        float h1[32];
#pragma unroll
        for (int o = 0; o < 32; o += 4) {
            float a0 = sB1[o], a1 = sB1[o + 1], a2 = sB1[o + 2], a3 = sB1[o + 3];
#pragma unroll
            for (int c = 0; c < 32; c += 4) {
                float4 w0 = *(const float4*)&sW1[(o    ) * 32 + c];
                float4 w1 = *(const float4*)&sW1[(o + 1) * 32 + c];
                float4 w2 = *(const float4*)&sW1[(o + 2) * 32 + c];
                float4 w3 = *(const float4*)&sW1[(o + 3) * 32 + c];
                float x0 = h[c], x1 = h[c + 1], x2 = h[c + 2], x3 = h[c + 3];
                a0 += x0 * w0.x + x1 * w0.y + x2 * w0.z + x3 * w0.w;
                a1 += x0 * w1.x + x1 * w1.y + x2 * w1.z + x3 * w1.w;
                a2 += x0 * w2.x + x1 * w2.y + x2 * w2.z + x3 * w2.w;
                a3 += x0 * w3.x + x1 * w3.y + x2 * w3.z + x3 * w3.w;
            }
            h1[o] = fmaxf(a0, 0.f); h1[o + 1] = fmaxf(a1, 0.f);
            h1[o + 2] = fmaxf(a2, 0.f); h1[o + 3] = fmaxf(a3, 0.f);
        }

        // att = W2 @ h1 + b2   (16x32 matvec)
        float att[16];
#pragma unroll
        for (int o = 0; o < 16; o += 4) {
            float a0 = sB2[o], a1 = sB2[o + 1], a2 = sB2[o + 2], a3 = sB2[o + 3];
#pragma unroll
            for (int c = 0; c < 32; c += 4) {
                float4 w0 = *(const float4*)&sW2[(o    ) * 32 + c];
                float4 w1 = *(const float4*)&sW2[(o + 1) * 32 + c];
                float4 w2 = *(const float4*)&sW2[(o + 2) * 32 + c];
                float4 w3 = *(const float4*)&sW2[(o + 3) * 32 + c];
                float x0 = h1[c], x1 = h1[c + 1], x2 = h1[c + 2], x3 = h1[c + 3];
                a0 += x0 * w0.x + x1 * w0.y + x2 * w0.z + x3 * w0.w;
                a1 += x0 * w1.x + x1 * w1.y + x2 * w1.z + x3 * w1.w;
                a2 += x0 * w2.x + x1 * w2.y + x2 * w2.z + x3 * w2.w;
                a3 += x0 * w3.x + x1 * w3.y + x2 * w3.z + x3 * w3.w;
            }
            att[o] = a0; att[o + 1] = a1; att[o + 2] = a2; att[o + 3] = a3;
        }

        // lane-local softmax over the 16 logits (scaled by dm/temp, temp=4)
        const float sc = dm * 0.25f;
#pragma unroll
        for (int i = 0; i < 16; ++i) att[i] *= sc;
        float mx = att[0];
#pragma unroll
        for (int i = 1; i < 16; ++i) mx = fmaxf(mx, att[i]);
        float s = 0.f;
        float p[16];
#pragma unroll
        for (int i = 0; i < 16; ++i) { p[i] = __expf(att[i] - mx); s += p[i]; }
        const float inv = 1.f / s;

        if (valid) {
            float* pr = prob_out + (size_t)e * 128 + hd;
            const float* vp = xv + (size_t)cl * 128 + hd;
            unsigned* ab = aggenc + (size_t)r * 128 + hd;
#pragma unroll
            for (int o2 = 0; o2 < 16; ++o2) {
                float pi = p[o2] * inv;
                pr[o2 * 8] = pi;
                float wv = pi * vp[o2 * 8];
                atomicMax(ab + o2 * 8, encf(wv));
            }
        }
    }
}

// ---------------------------------------------------------------- small elementwise kernels

__global__ __launch_bounds__(256) void k_ncat(const float* __restrict__ x,
                                              const unsigned* __restrict__ aggenc,
                                              float* __restrict__ ncat, int N) {
    int i = blockIdx.x * 256 + threadIdx.x;
    if (i >= N * 256) return;
    int n = i >> 8, c = i & 255;
    float v;
    if (c < 128) v = x[n * 128 + c];
    else {
        unsigned u = aggenc[n * 128 + c - 128];
        v = (u == ENC_NEGINF) ? 0.f : decf(u);
    }
    ncat[i] = v;
}

__global__ __launch_bounds__(256) void k_cat2(const float* __restrict__ outf,
                                              const float* __restrict__ incf,
                                              const int* __restrict__ rowcnt,
                                              const int* __restrict__ colcnt,
                                              float* __restrict__ cat2, int N) {
    int i = blockIdx.x * 256 + threadIdx.x;
    if (i >= N * 256) return;
    int n = i >> 8, c = i & 255;
    float v;
    if (c < 128) v = outf[n * 128 + c] / fmaxf((float)rowcnt[n], 1.f);
    else v = incf[n * 128 + c - 128] / fmaxf((float)colcnt[n], 1.f);
    cat2[i] = v;
}

__global__ __launch_bounds__(256) void k_final(const float* __restrict__ un,
                                               const float* __restrict__ eatt,
                                               float* __restrict__ dst, int NC) {
    int i = blockIdx.x * 256 + threadIdx.x;
    if (i >= NC) return;
    dst[i] = fmaxf(un[i], 0.f) * eatt[i];
}

// ---------------------------------------------------------------- host orchestration

extern "C" void kernel_launch(void* const* d_in, const int* in_sizes, int n_in,
                              void* d_out, int out_size, void* d_ws, size_t ws_size,
                              hipStream_t stream) {
    const float* node_feature = (const float*)d_in[0];
    const float* edge_feature = (const float*)d_in[1];
    const int* edges = (const int*)d_in[2];
    const float* desc = (const float*)d_in[3];
    const float* qW = (const float*)d_in[4];
    const float* qB = (const float*)d_in[5];
    const float* kW = (const float*)d_in[6];
    const float* kB = (const float*)d_in[7];
    const float* vW = (const float*)d_in[8];
    const float* vB = (const float*)d_in[9];
    const float* dW1 = (const float*)d_in[10];
    const float* dB1 = (const float*)d_in[11];
    const float* dW2 = (const float*)d_in[12];
    const float* dB2 = (const float*)d_in[13];
    const float* eW1 = (const float*)d_in[14];
    const float* eB1 = (const float*)d_in[15];
    const float* eW2 = (const float*)d_in[16];
    const float* eB2 = (const float*)d_in[17];
    const float* attW1 = (const float*)d_in[18];
    const float* attB1 = (const float*)d_in[19];
    const float* attW2 = (const float*)d_in[20];
    const float* attB2 = (const float*)d_in[21];
    const float* nW1 = (const float*)d_in[22];
    const float* nB1 = (const float*)d_in[23];
    const float* nW2 = (const float*)d_in[24];
    const float* nB2 = (const float*)d_in[25];
    const float* aW = (const float*)d_in[26];
    const float* aB = (const float*)d_in[27];

    const int N = in_sizes[0] / 128;
    const int E = in_sizes[2] / 2;
    const int L = 2;
    const int* row = edges;
    const int* col = edges + E;

    char* wsp = (char*)d_ws;
    auto alloc = [&](size_t bytes) {
        char* p = wsp;
        wsp += (bytes + 255) & ~(size_t)255;
        return p;
    };
    unsigned* hashK = (unsigned*)alloc((size_t)HS * 4);
    int* hashV = (int*)alloc((size_t)HS * 4);
    int* ridx = (int*)alloc((size_t)E * 4);
    int* rowcnt = (int*)alloc((size_t)N * 4);
    int* colcnt = (int*)alloc((size_t)N * 4);
    float* xq = (float*)alloc((size_t)N * 128 * 4);
    float* xv = (float*)alloc((size_t)N * 128 * 4);
    float* xa = (float*)alloc((size_t)N * 384 * 4);
    float* xb = (float*)alloc((size_t)N * 384 * 4);
    float* kbuf = (float*)alloc((size_t)E * 128 * 4);
    float* efbuf = (float*)alloc((size_t)E * 128 * 4);
    float* dmbuf = (float*)alloc((size_t)E * 4);
    const int CH = 32000;
    float* h1c = (float*)alloc((size_t)CH * 384 * 4);
    unsigned* aggenc = (unsigned*)alloc((size_t)N * 128 * 4);
    float* ncat = (float*)alloc((size_t)N * 256 * 4);
    float* nh1 = (float*)alloc((size_t)N * 256 * 4);
    float* un = (float*)alloc((size_t)N * 128 * 4);
    float* outf = (float*)alloc((size_t)N * 128 * 4);
    float* incf = (float*)alloc((size_t)N * 128 * 4);
    float* cat2 = (float*)alloc((size_t)N * 256 * 4);
    float* eattb = (float*)alloc((size_t)N * 128 * 4);
    float* xbuf = (float*)alloc((size_t)N * 128 * 4);
    unsigned short* wt1_hi = (unsigned short*)alloc((size_t)384 * 256 * 2);
    unsigned short* wt1_lo = (unsigned short*)alloc((size_t)384 * 256 * 2);
    unsigned short* wt2_hi = (unsigned short*)alloc((size_t)128 * 384 * 2);
    unsigned short* wt2_lo = (unsigned short*)alloc((size_t)128 * 384 * 2);
    unsigned short* wtk_hi = (unsigned short*)alloc((size_t)128 * 128 * 2);
    unsigned short* wtk_lo = (unsigned short*)alloc((size_t)128 * 128 * 2);

    float* out_x = (float*)d_out;
    float* out_ef = out_x + (size_t)N * 128;
    float* out_prob = out_ef + (size_t)E * 128;

    k_init_static<<<(HS + 255) / 256, 256, 0, stream>>>(hashK, hashV, rowcnt, colcnt, N);
    k_hash_insert<<<(E + 255) / 256, 256, 0, stream>>>(row, col, hashK, hashV, N, E);
    k_hash_lookup<<<(E + 255) / 256, 256, 0, stream>>>(row, col, hashK, hashV, ridx, rowcnt, colcnt, N, E);

    for (int l = 0; l < L; ++l) {
        const float* x_cur = (l == 0) ? node_feature : xbuf;
        const float* ef_cur = (l == 0) ? edge_feature : efbuf;
        const bool last = (l == L - 1);

        const float* qW_l = qW + (size_t)l * 128 * 128;
        const float* qB_l = qB + (size_t)l * 128;
        const float* kW_l = kW + (size_t)l * 128 * 128;
        const float* kB_l = kB + (size_t)l * 128;
        const float* vW_l = vW + (size_t)l * 128 * 128;
        const float* vB_l = vB + (size_t)l * 128;
        const float* dW1_l = dW1 + (size_t)l * 128;
        const float* dB1_l = dB1 + (size_t)l * 32;
        const float* dW2_l = dW2 + (size_t)l * 32;
        const float* dB2_l = dB2 + (size_t)l * 1;
        const float* eW1_l = eW1 + (size_t)l * 512 * 384;
        const float* eB1_l = eB1 + (size_t)l * 384;
        const float* eW2_l = eW2 + (size_t)l * 384 * 128;
        const float* eB2_l = eB2 + (size_t)l * 128;
        const float* attW1_l = attW1 + (size_t)l * 32 * 32;
        const float* attB1_l = attB1 + (size_t)l * 32;
        const float* attW2_l = attW2 + (size_t)l * 16 * 32;
        const float* attB2_l = attB2 + (size_t)l * 16;
        const float* nW1_l = nW1 + (size_t)l * 256 * 256;
        const float* nB1_l = nB1 + (size_t)l * 256;
        const float* nW2_l = nW2 + (size_t)l * 256 * 128;
        const float* nB2_l = nB2 + (size_t)l * 128;
        const float* aW_l = aW + (size_t)l * 256 * 128;
        const float* aB_l = aB + (size_t)l * 128;

        // weight prep (transpose + bf16 split)
        k_prep_wt<<<(256 * 384 + 255) / 256, 256, 0, stream>>>(eW1_l + (size_t)128 * 384, wt1_hi, wt1_lo, 256, 384);
        k_prep_wt<<<(384 * 128 + 255) / 256, 256, 0, stream>>>(eW2_l, wt2_hi, wt2_lo, 384, 128);
        k_prep_wt<<<(128 * 128 + 255) / 256, 256, 0, stream>>>(kW_l, wtk_hi, wtk_lo, 128, 128);

        k_layer_init<<<(N * 128 + 255) / 256, 256, 0, stream>>>(aggenc, outf, incf, N * 128);

        // distance-gate MLP precompute (per edge)
        k_dm<<<(E + 255) / 256, 256, 0, stream>>>(desc, row, col, dW1_l, dB1_l, dW2_l, dB2_l, dmbuf, E);

        int gy_n = (N + 63) / 64;
        // per-node precomputes (fp32)
        k_gemm<0><<<dim3(2, gy_n), 256, 0, stream>>>(x_cur, qW_l, qB_l, xq, N, 128, 128, 128, 128, 128);
        k_gemm<0><<<dim3(2, gy_n), 256, 0, stream>>>(x_cur, vW_l, vB_l, xv, N, 128, 128, 128, 128, 128);
        k_gemm<0><<<dim3(6, gy_n), 256, 0, stream>>>(x_cur, eW1_l, nullptr, xa, N, 384, 128, 128, 384, 384);
        k_gemm<0><<<dim3(6, gy_n), 256, 0, stream>>>(x_cur, eW1_l + (size_t)384 * 384, nullptr, xb, N, 384, 128, 128, 384, 384);
        // per-edge k projection (MFMA)
        k_mfma_gemm<2, 4><<<dim3(1, (E + 127) / 128), 256, 0, stream>>>(
            ef_cur, nullptr, wtk_hi, wtk_lo, kB_l, nullptr, nullptr, nullptr, nullptr,
            kbuf, nullptr, nullptr, 0, E, 0);
        // attention + prob + segment-max (lane-per-(edge,head))
        k_attn<<<2048, 256, 0, stream>>>(xq, kbuf, xv, row, col, attW1_l, attB1_l, attW2_l, attB2_l,
                                         dmbuf, out_prob + (size_t)l * E * 128, aggenc, E);
        // edge MLP in chunks (MFMA)
        for (int cb = 0; cb < E; cb += CH) {
            int mrows = (E - cb < CH) ? (E - cb) : CH;
            int gy = (mrows + 127) / 128;
            k_mfma_gemm<0, 8><<<dim3(3, gy), 256, 0, stream>>>(
                ef_cur, ridx, wt1_hi, wt1_lo, eB1_l, xa, xb, row, col,
                h1c, nullptr, nullptr, cb, mrows, 0);
            k_mfma_gemm<1, 12><<<dim3(1, gy), 256, 0, stream>>>(
                h1c, nullptr, wt2_hi, wt2_lo, eB2_l, nullptr, nullptr, row, col,
                last ? out_ef : efbuf, outf, incf, cb, mrows, last ? 0 : 1);
        }
        // node update
        k_ncat<<<(N * 256 + 255) / 256, 256, 0, stream>>>(x_cur, aggenc, ncat, N);
        k_gemm<1><<<dim3(4, gy_n), 256, 0, stream>>>(ncat, nW1_l, nB1_l, nh1, N, 256, 256, 256, 256, 256);
        k_gemm<0><<<dim3(2, gy_n), 256, 0, stream>>>(nh1, nW2_l, nB2_l, un, N, 128, 256, 256, 128, 128);
        k_cat2<<<(N * 256 + 255) / 256, 256, 0, stream>>>(outf, incf, rowcnt, colcnt, cat2, N);
        k_gemm<2><<<dim3(2, gy_n), 256, 0, stream>>>(cat2, aW_l, aB_l, eattb, N, 128, 256, 256, 128, 128);
        k_final<<<(N * 128 + 255) / 256, 256, 0, stream>>>(un, eattb, last ? out_x : xbuf, N * 128);
    }
}

// Round 2
// 2267.497 us; speedup vs baseline: 1.2607x; 1.2607x over previous
//
#include <hip/hip_runtime.h>
#include <math.h>

#define HS 524288
#define HSM (HS - 1)
#define ENC_NEGINF 0x007FFFFFu

__device__ __forceinline__ unsigned encf(float f) {
    unsigned b = __float_as_uint(f);
    return (b & 0x80000000u) ? ~b : (b | 0x80000000u);
}
__device__ __forceinline__ float decf(unsigned u) {
    return __uint_as_float((u & 0x80000000u) ? (u & 0x7FFFFFFFu) : ~u);
}

__device__ __forceinline__ unsigned short f2bf(float x) {
    unsigned u = __float_as_uint(x);
    unsigned r = u + 0x7FFFu + ((u >> 16) & 1u);
    return (unsigned short)(r >> 16);
}
__device__ __forceinline__ float bf2f(unsigned short h) {
    return __uint_as_float(((unsigned)h) << 16);
}

using bfrag = __attribute__((ext_vector_type(8))) short;
using ffrag = __attribute__((ext_vector_type(4))) float;

// split 8 fp32 into hi/lo bf16 fragments
__device__ __forceinline__ void split8(const float* f, bfrag& hi, bfrag& lo) {
#pragma unroll
    for (int j = 0; j < 8; ++j) {
        unsigned short h = f2bf(f[j]);
        hi[j] = (short)h;
        lo[j] = (short)f2bf(f[j] - bf2f(h));
    }
}

// ---------------------------------------------------------------- setup kernels

__global__ __launch_bounds__(256) void k_init_static(unsigned* hashK, int* hashV,
                                                     int* rowcnt, int* colcnt, int N) {
    int i = blockIdx.x * 256 + threadIdx.x;
    if (i < HS) { hashK[i] = 0xFFFFFFFFu; hashV[i] = 0x7FFFFFFF; }
    if (i < N) { rowcnt[i] = 0; colcnt[i] = 0; }
}

__global__ __launch_bounds__(256) void k_hash_insert(const int* __restrict__ row,
                                                     const int* __restrict__ col,
                                                     unsigned* hashK, int* hashV, int N, int E) {
    int e = blockIdx.x * 256 + threadIdx.x;
    if (e >= E) return;
    unsigned key = (unsigned)row[e] * (unsigned)N + (unsigned)col[e];
    unsigned h = (key * 2654435761u) >> 13; h &= HSM;
    while (true) {
        unsigned prev = atomicCAS(&hashK[h], 0xFFFFFFFFu, key);
        if (prev == 0xFFFFFFFFu || prev == key) { atomicMin(&hashV[h], e); break; }
        h = (h + 1) & HSM;
    }
}

__global__ __launch_bounds__(256) void k_hash_lookup(const int* __restrict__ row,
                                                     const int* __restrict__ col,
                                                     const unsigned* __restrict__ hashK,
                                                     const int* __restrict__ hashV,
                                                     int* __restrict__ ridx,
                                                     int* rowcnt, int* colcnt, int N, int E) {
    int e = blockIdx.x * 256 + threadIdx.x;
    if (e >= E) return;
    int r = row[e], c = col[e];
    unsigned rkey = (unsigned)c * (unsigned)N + (unsigned)r;
    unsigned h = (rkey * 2654435761u) >> 13; h &= HSM;
    int res = -1;
    while (true) {
        unsigned kk = hashK[h];
        if (kk == rkey) { res = hashV[h]; break; }
        if (kk == 0xFFFFFFFFu) break;
        h = (h + 1) & HSM;
    }
    ridx[e] = res;
    atomicAdd(&rowcnt[r], 1);
    atomicAdd(&colcnt[c], 1);
}

__global__ __launch_bounds__(256) void k_layer_init(unsigned* aggenc, float* outf, float* incf, int NC) {
    int i = blockIdx.x * 256 + threadIdx.x;
    if (i >= NC) return;
    aggenc[i] = ENC_NEGINF;
    outf[i] = 0.f;
    incf[i] = 0.f;
}

// Weight prep: src fp32 [K][Nn] row-major -> whi/wlo bf16 [Nn][K] (transposed + split)
__global__ __launch_bounds__(256) void k_prep_wt(const float* __restrict__ src,
                                                 unsigned short* __restrict__ whi,
                                                 unsigned short* __restrict__ wlo,
                                                 int K, int Nn) {
    int idx = blockIdx.x * 256 + threadIdx.x;
    if (idx >= K * Nn) return;
    int k = idx / Nn, n = idx - k * Nn;
    float v = src[idx];
    unsigned short h = f2bf(v);
    float hf = bf2f(h);
    unsigned short l = f2bf(v - hf);
    whi[(size_t)n * K + k] = h;
    wlo[(size_t)n * K + k] = l;
}

// ---------------------------------------------------------------- generic fp32 GEMM (node-side)
template <int ACT>
__global__ __launch_bounds__(256) void k_gemm(const float* __restrict__ A,
                                              const float* __restrict__ B,
                                              const float* __restrict__ bias,
                                              float* __restrict__ C,
                                              int M, int Nd, int K, int lda, int ldb, int ldc) {
    __shared__ float As[16][64];
    __shared__ float Bs[16][64];
    const int tid = threadIdx.x;
    const int bm = blockIdx.y * 64, bn = blockIdx.x * 64;
    const int tx = tid & 15, ty = tid >> 4;
    const int mload = tid >> 2, k4 = (tid & 3) << 2;
    const int kload = tid >> 4, n4 = (tid & 15) << 2;
    float acc[4][4] = {};
    const int gmload = bm + mload;
    const bool avalid = (gmload < M);
    const float* aptr = A + (size_t)(avalid ? gmload : (M - 1)) * lda + k4;
    const float* bptr = B + (size_t)kload * ldb + bn + n4;
    for (int kb = 0; kb < K; kb += 16) {
        float4 av = avalid ? *(const float4*)(aptr + kb) : make_float4(0.f, 0.f, 0.f, 0.f);
        As[k4 + 0][mload] = av.x; As[k4 + 1][mload] = av.y;
        As[k4 + 2][mload] = av.z; As[k4 + 3][mload] = av.w;
        *(float4*)&Bs[kload][n4] = *(const float4*)(bptr + (size_t)kb * ldb);
        __syncthreads();
#pragma unroll
        for (int k = 0; k < 16; ++k) {
            float4 a = *(const float4*)&As[k][ty << 2];
            float4 b = *(const float4*)&Bs[k][tx << 2];
            acc[0][0] += a.x * b.x; acc[0][1] += a.x * b.y; acc[0][2] += a.x * b.z; acc[0][3] += a.x * b.w;
            acc[1][0] += a.y * b.x; acc[1][1] += a.y * b.y; acc[1][2] += a.y * b.z; acc[1][3] += a.y * b.w;
            acc[2][0] += a.z * b.x; acc[2][1] += a.z * b.y; acc[2][2] += a.z * b.z; acc[2][3] += a.z * b.w;
            acc[3][0] += a.w * b.x; acc[3][1] += a.w * b.y; acc[3][2] += a.w * b.z; acc[3][3] += a.w * b.w;
        }
        __syncthreads();
    }
#pragma unroll
    for (int i = 0; i < 4; ++i) {
        int gm = bm + (ty << 2) + i;
        if (gm >= M) continue;
        float* crow = C + (size_t)gm * ldc;
#pragma unroll
        for (int j = 0; j < 4; ++j) {
            int gn = bn + (tx << 2) + j;
            float v = acc[i][j];
            if (bias) v += bias[gn];
            if (ACT == 1) v = fmaxf(v, 0.f);
            if (ACT == 2) v = 1.f / (1.f + __expf(-v));
            crow[gn] = v;
        }
    }
}

// ---------------------------------------------------------------- MFMA split-bf16 GEMM
// 128x128 tile, BK=32, 4 waves (2x2), each wave 64x64 via 16x16x32 bf16 MFMA.
// 3-term split: D += Ahi*Bhi + Alo*Bhi + Ahi*Blo  (error ~2^-17, fp32-equivalent).

#define LDP 40   // LDS row pitch in shorts (BK 32 + 8): 80B rows, 16B-aligned, ~2-way banks

template <int MODE, int KSTEPS>
__global__ __launch_bounds__(256) void k_mfma_gemm(const float* __restrict__ Asrc,
                                                   const int* __restrict__ ridx,
                                                   const unsigned short* __restrict__ Bhi,
                                                   const unsigned short* __restrict__ Blo,
                                                   const float* __restrict__ bias,
                                                   const float* __restrict__ xa,
                                                   const float* __restrict__ xb,
                                                   const int* __restrict__ rowArr,
                                                   const int* __restrict__ colArr,
                                                   float* __restrict__ outC,
                                                   float* __restrict__ outf,
                                                   float* __restrict__ incf,
                                                   int edgeBase, int Mrows, int reluOut) {
    constexpr int K = KSTEPS * 32;
    __shared__ unsigned short Ah[128 * LDP];
    __shared__ unsigned short Al[128 * LDP];
    __shared__ unsigned short Bh[128 * LDP];
    __shared__ unsigned short Bl[128 * LDP];

    const int tid = threadIdx.x;
    const int bm = blockIdx.y * 128;
    const int bx = blockIdx.x;

    const int sr = tid >> 1;
    const int kh = (tid & 1) * 16;

    const float* p0;
    const float* p1 = nullptr;
    {
        int rc = min(bm + sr, Mrows - 1);
        if (MODE == 0) {
            int e = edgeBase + rc;
            p0 = Asrc + (size_t)e * 128;
            int rv = ridx[e];
            p1 = (rv >= 0) ? (Asrc + (size_t)rv * 128) : nullptr;
        } else if (MODE == 1) {
            p0 = Asrc + (size_t)rc * 384;
        } else {
            p0 = Asrc + (size_t)rc * 128;
        }
    }
    const unsigned short* bhp = Bhi + (size_t)(bx * 128 + sr) * K + kh;
    const unsigned short* blp = Blo + (size_t)(bx * 128 + sr) * K + kh;

    const int wid = tid >> 6;
    const int lane = tid & 63;
    const int wr0 = (wid >> 1) * 64;
    const int wc0 = (wid & 1) * 64;
    const int lm = lane & 15;
    const int lk = (lane >> 4) * 8;

    ffrag acc[4][4];
#pragma unroll
    for (int i = 0; i < 4; ++i)
#pragma unroll
        for (int j = 0; j < 4; ++j)
            acc[i][j] = (ffrag){0.f, 0.f, 0.f, 0.f};

    unsigned short* AhW = &Ah[sr * LDP + kh];
    unsigned short* AlW = &Al[sr * LDP + kh];
    unsigned short* BhW = &Bh[sr * LDP + kh];
    unsigned short* BlW = &Bl[sr * LDP + kh];

    for (int ks = 0; ks < KSTEPS; ++ks) {
        const int kb = ks * 32;
        const float* ap;
        if (MODE == 0) ap = (kb < 128) ? (p0 + kb) : (p1 ? p1 + (kb - 128) : nullptr);
        else ap = p0 + kb;
#pragma unroll
        for (int c = 0; c < 4; ++c) {
            float4 f = ap ? *(const float4*)(ap + kh + c * 4) : make_float4(0.f, 0.f, 0.f, 0.f);
            ushort4 h, l;
            h.x = f2bf(f.x); l.x = f2bf(f.x - bf2f(h.x));
            h.y = f2bf(f.y); l.y = f2bf(f.y - bf2f(h.y));
            h.z = f2bf(f.z); l.z = f2bf(f.z - bf2f(h.z));
            h.w = f2bf(f.w); l.w = f2bf(f.w - bf2f(h.w));
            *(ushort4*)(AhW + c * 4) = h;
            *(ushort4*)(AlW + c * 4) = l;
        }
        {
            uint4 b0 = *(const uint4*)(bhp + kb);
            uint4 b1 = *(const uint4*)(bhp + kb + 8);
            uint4 c0 = *(const uint4*)(blp + kb);
            uint4 c1 = *(const uint4*)(blp + kb + 8);
            *(uint4*)(BhW) = b0; *(uint4*)(BhW + 8) = b1;
            *(uint4*)(BlW) = c0; *(uint4*)(BlW + 8) = c1;
        }
        __syncthreads();
        bfrag a_h[4], a_l[4], b_h[4], b_l[4];
#pragma unroll
        for (int mt = 0; mt < 4; ++mt) {
            int base = (wr0 + mt * 16 + lm) * LDP + lk;
            a_h[mt] = *(const bfrag*)&Ah[base];
            a_l[mt] = *(const bfrag*)&Al[base];
        }
#pragma unroll
        for (int nt = 0; nt < 4; ++nt) {
            int base = (wc0 + nt * 16 + lm) * LDP + lk;
            b_h[nt] = *(const bfrag*)&Bh[base];
            b_l[nt] = *(const bfrag*)&Bl[base];
        }
#pragma unroll
        for (int mt = 0; mt < 4; ++mt)
#pragma unroll
            for (int nt = 0; nt < 4; ++nt) {
                acc[mt][nt] = __builtin_amdgcn_mfma_f32_16x16x32_bf16(a_h[mt], b_h[nt], acc[mt][nt], 0, 0, 0);
                acc[mt][nt] = __builtin_amdgcn_mfma_f32_16x16x32_bf16(a_l[mt], b_h[nt], acc[mt][nt], 0, 0, 0);
                acc[mt][nt] = __builtin_amdgcn_mfma_f32_16x16x32_bf16(a_h[mt], b_l[nt], acc[mt][nt], 0, 0, 0);
            }
        __syncthreads();
    }

    float bv[4];
#pragma unroll
    for (int nt = 0; nt < 4; ++nt) bv[nt] = bias[bx * 128 + wc0 + nt * 16 + lm];

#pragma unroll
    for (int mt = 0; mt < 4; ++mt) {
#pragma unroll
        for (int i = 0; i < 4; ++i) {
            int grow = bm + wr0 + mt * 16 + (lane >> 4) * 4 + i;
            if (grow >= Mrows) continue;
            if (MODE == 0) {
                int e = edgeBase + grow;
                size_t re = (size_t)rowArr[e] * 384;
                size_t ce = (size_t)colArr[e] * 384;
                float* crow = outC + (size_t)grow * 384;
#pragma unroll
                for (int nt = 0; nt < 4; ++nt) {
                    int gcol = bx * 128 + wc0 + nt * 16 + lm;
                    float v = acc[mt][nt][i] + bv[nt] + xa[re + gcol] + xb[ce + gcol];
                    crow[gcol] = fmaxf(v, 0.f);
                }
            } else if (MODE == 1) {
                int e = edgeBase + grow;
                size_t re = (size_t)rowArr[e] * 128;
                size_t ce = (size_t)colArr[e] * 128;
                float* crow = outC + (size_t)e * 128;
#pragma unroll
                for (int nt = 0; nt < 4; ++nt) {
                    int gcol = wc0 + nt * 16 + lm;
                    float v = acc[mt][nt][i] + bv[nt];
                    atomicAdd(&outf[re + gcol], v);
                    atomicAdd(&incf[ce + gcol], v);
                    crow[gcol] = reluOut ? fmaxf(v, 0.f) : v;
                }
            } else {
                float* crow = outC + (size_t)grow * 128;
#pragma unroll
                for (int nt = 0; nt < 4; ++nt) {
                    int gcol = wc0 + nt * 16 + lm;
                    crow[gcol] = acc[mt][nt][i] + bv[nt];
                }
            }
        }
    }
}

// ---------------------------------------------------------------- distance-gate MLP precompute

__global__ __launch_bounds__(256) void k_dm(const float* __restrict__ desc,
                                            const int* __restrict__ row,
                                            const int* __restrict__ col,
                                            const float* __restrict__ dW1,
                                            const float* __restrict__ dB1,
                                            const float* __restrict__ dW2,
                                            const float* __restrict__ dB2,
                                            float* __restrict__ dmbuf, int E) {
    __shared__ float sw[128];
    __shared__ float sb[32];
    __shared__ float sv[32];
    for (int i = threadIdx.x; i < 128; i += 256) sw[i] = dW1[i];
    if (threadIdx.x < 32) { sb[threadIdx.x] = dB1[threadIdx.x]; sv[threadIdx.x] = dW2[threadIdx.x]; }
    __syncthreads();
    const float db2v = dB2[0];
    for (int e = blockIdx.x * 256 + threadIdx.x; e < E; e += gridDim.x * 256) {
        int r = row[e], c = col[e];
        float dx = desc[r * 8 + 0] - desc[c * 8 + 0];
        float dy = desc[r * 8 + 1] - desc[c * 8 + 1];
        float dz = desc[r * 8 + 2] - desc[c * 8 + 2];
        float dist = sqrtf(dx * dx + dy * dy + dz * dz);
        float acc = db2v;
#pragma unroll
        for (int j = 0; j < 32; ++j) {
            float t = sb[j] + dx * sw[j] + dy * sw[32 + j] + dz * sw[64 + j] + dist * sw[96 + j];
            acc += fmaxf(t, 0.f) * sv[j];
        }
        dmbuf[e] = 1.f / (1.f + __expf(-acc));
    }
}

// ---------------------------------------------------------------- attention kernel (MFMA)
// 2 edges per wave-iteration = 16 (edge,head) rows per 16x16x32 MFMA tile.
// matvec1: D1[o][eh] = W1[o][c] · h[eh][c]  (A = W1 split-bf16, resident in regs;
//          B = h^T gathered from xq/kbuf). 2 o-tiles x 3 split terms = 6 MFMAs.
// LDS bounce (pitch 36 + XOR chunk swizzle, conflict-free) transposes h1 into the
// B-fragment for matvec2: D2[o2][eh] = W2[o2][o] · h1[eh][o], 3 MFMAs.
// Softmax over o2 = 4 shfl_xor (lanes lm, lm+16, lm+32, lm+48 hold one eh column).

__global__ __launch_bounds__(256) void k_attn(const float* __restrict__ xq,
                                              const float* __restrict__ kbuf,
                                              const float* __restrict__ xv,
                                              const int* __restrict__ row,
                                              const int* __restrict__ col,
                                              const float* __restrict__ attW1,
                                              const float* __restrict__ attB1,
                                              const float* __restrict__ attW2,
                                              const float* __restrict__ attB2,
                                              const float* __restrict__ dmbuf,
                                              float* __restrict__ prob_out,
                                              unsigned* __restrict__ aggenc, int E) {
    __shared__ float sh1[4][16 * 36];   // per-wave h1 bounce (2304 B each)

    const int tid = threadIdx.x;
    const int wv = tid >> 6;
    const int lane = tid & 63;
    const int lm = lane & 15;       // eh index within tile (edge pair: lm>>3, head: lm&7)
    const int lk = lane >> 4;       // k-group
    float* bounce = sh1[wv];
    const int swz = (lm & 3) << 1;  // XOR chunk swizzle (even -> preserves pair adjacency)

    // ---- resident weight fragments (A-frag layout: lane holds W[row=lm(+t*16)][k=lk*8+j])
    bfrag w1h[2], w1l[2], w2h, w2l;
    {
        float tmp[8];
#pragma unroll
        for (int t = 0; t < 2; ++t) {
            const float* p = attW1 + (size_t)(t * 16 + lm) * 32 + lk * 8;
            *(float4*)&tmp[0] = *(const float4*)p;
            *(float4*)&tmp[4] = *(const float4*)(p + 4);
            split8(tmp, w1h[t], w1l[t]);
        }
        const float* p = attW2 + (size_t)lm * 32 + lk * 8;
        *(float4*)&tmp[0] = *(const float4*)p;
        *(float4*)&tmp[4] = *(const float4*)(p + 4);
        split8(tmp, w2h, w2l);
    }
    // biases: D rows are o = t*16 + lk*4 + r
    const float4 b1v0 = *(const float4*)(attB1 + lk * 4);
    const float4 b1v1 = *(const float4*)(attB1 + 16 + lk * 4);
    const float4 b2v = *(const float4*)(attB2 + lk * 4);

    const int gw = (blockIdx.x * 256 + tid) >> 6;
    const int nw = (gridDim.x * 256) >> 6;
    const int ngrp = (E + 1) >> 1;

    for (int g = gw; g < ngrp; g += nw) {
        const int e0 = g * 2;
        const int eL = e0 + (lm >> 3);          // this lane's edge
        const int ev = min(eL, E - 1);
        const int hd = lm & 7;
        const int rn = row[ev], cn = col[ev];

        // ---- gather B-frag of h^T: lane needs h[eh=lm][c=lk*8+j]
        //      c<16 -> xq[rn][c*8+hd]; c>=16 -> kbuf[ev][(c-16)*8+hd]
        float hf[8];
        {
            const float* base = (lk < 2)
                ? (xq + (size_t)rn * 128 + hd + lk * 64)
                : (kbuf + (size_t)ev * 128 + hd + (lk - 2) * 64);
#pragma unroll
            for (int j = 0; j < 8; ++j) hf[j] = base[j * 8];
        }
        bfrag hh, hl;
        split8(hf, hh, hl);

        // ---- matvec1: h1 = relu(W1 h + b1), accumulator pre-loaded with bias
        ffrag d0 = (ffrag){b1v0.x, b1v0.y, b1v0.z, b1v0.w};
        ffrag d1 = (ffrag){b1v1.x, b1v1.y, b1v1.z, b1v1.w};
        d0 = __builtin_amdgcn_mfma_f32_16x16x32_bf16(w1h[0], hh, d0, 0, 0, 0);
        d1 = __builtin_amdgcn_mfma_f32_16x16x32_bf16(w1h[1], hh, d1, 0, 0, 0);
        d0 = __builtin_amdgcn_mfma_f32_16x16x32_bf16(w1l[0], hh, d0, 0, 0, 0);
        d1 = __builtin_amdgcn_mfma_f32_16x16x32_bf16(w1l[1], hh, d1, 0, 0, 0);
        d0 = __builtin_amdgcn_mfma_f32_16x16x32_bf16(w1h[0], hl, d0, 0, 0, 0);
        d1 = __builtin_amdgcn_mfma_f32_16x16x32_bf16(w1h[1], hl, d1, 0, 0, 0);
#pragma unroll
        for (int r = 0; r < 4; ++r) { d0[r] = fmaxf(d0[r], 0.f); d1[r] = fmaxf(d1[r], 0.f); }

        // ---- LDS bounce: write h1[o=t*16+lk*4+r][eh=lm] -> bounce[eh][o] (swizzled chunks)
        *(float4*)&bounce[lm * 36 + ((lk) ^ swz) * 4] = (float4){d0[0], d0[1], d0[2], d0[3]};
        *(float4*)&bounce[lm * 36 + ((4 + lk) ^ swz) * 4] = (float4){d1[0], d1[1], d1[2], d1[3]};
        __builtin_amdgcn_wave_barrier();
        // read B-frag of h1^T: lane needs h1[eh=lm][o=lk*8+j] -> chunks {2lk, 2lk+1}
        float h1f[8];
        *(float4*)&h1f[0] = *(const float4*)&bounce[lm * 36 + ((2 * lk) ^ swz) * 4];
        *(float4*)&h1f[4] = *(const float4*)&bounce[lm * 36 + ((2 * lk + 1) ^ swz) * 4];
        __builtin_amdgcn_wave_barrier();
        bfrag h1h, h1l;
        split8(h1f, h1h, h1l);

        // ---- matvec2: att = W2 h1 + b2
        ffrag a = (ffrag){b2v.x, b2v.y, b2v.z, b2v.w};
        a = __builtin_amdgcn_mfma_f32_16x16x32_bf16(w2h, h1h, a, 0, 0, 0);
        a = __builtin_amdgcn_mfma_f32_16x16x32_bf16(w2l, h1h, a, 0, 0, 0);
        a = __builtin_amdgcn_mfma_f32_16x16x32_bf16(w2h, h1l, a, 0, 0, 0);

        // ---- scale + softmax over o2 (rows; lanes lm,lm+16,lm+32,lm+48 hold one eh col)
        const float sc = dmbuf[ev] * 0.25f;
        float t0 = a[0] * sc, t1 = a[1] * sc, t2 = a[2] * sc, t3 = a[3] * sc;
        float mx = fmaxf(fmaxf(t0, t1), fmaxf(t2, t3));
        mx = fmaxf(mx, __shfl_xor(mx, 16, 64));
        mx = fmaxf(mx, __shfl_xor(mx, 32, 64));
        float x0 = __expf(t0 - mx), x1 = __expf(t1 - mx);
        float x2 = __expf(t2 - mx), x3 = __expf(t3 - mx);
        float s = x0 + x1 + x2 + x3;
        s += __shfl_xor(s, 16, 64);
        s += __shfl_xor(s, 32, 64);
        const float inv = 1.f / s;
        x0 *= inv; x1 *= inv; x2 *= inv; x3 *= inv;

        // ---- outputs: prob + segment-max(prob*v).  o2 = lk*4 + r
        if (eL < E) {
            const int ob = lk * 4;
            float* pr = prob_out + (size_t)eL * 128 + hd;
            const float* vp = xv + (size_t)cn * 128 + hd;
            unsigned* ab = aggenc + (size_t)rn * 128 + hd;
            pr[(ob + 0) * 8] = x0;
            pr[(ob + 1) * 8] = x1;
            pr[(ob + 2) * 8] = x2;
            pr[(ob + 3) * 8] = x3;
            atomicMax(&ab[(ob + 0) * 8], encf(x0 * vp[(ob + 0) * 8]));
            atomicMax(&ab[(ob + 1) * 8], encf(x1 * vp[(ob + 1) * 8]));
            atomicMax(&ab[(ob + 2) * 8], encf(x2 * vp[(ob + 2) * 8]));
            atomicMax(&ab[(ob + 3) * 8], encf(x3 * vp[(ob + 3) * 8]));
        }
    }
}

// ---------------------------------------------------------------- small elementwise kernels

__global__ __launch_bounds__(256) void k_ncat(const float* __restrict__ x,
                                              const unsigned* __restrict__ aggenc,
                                              float* __restrict__ ncat, int N) {
    int i = blockIdx.x * 256 + threadIdx.x;
    if (i >= N * 256) return;
    int n = i >> 8, c = i & 255;
    float v;
    if (c < 128) v = x[n * 128 + c];
    else {
        unsigned u = aggenc[n * 128 + c - 128];
        v = (u == ENC_NEGINF) ? 0.f : decf(u);
    }
    ncat[i] = v;
}

__global__ __launch_bounds__(256) void k_cat2(const float* __restrict__ outf,
                                              const float* __restrict__ incf,
                                              const int* __restrict__ rowcnt,
                                              const int* __restrict__ colcnt,
                                              float* __restrict__ cat2, int N) {
    int i = blockIdx.x * 256 + threadIdx.x;
    if (i >= N * 256) return;
    int n = i >> 8, c = i & 255;
    float v;
    if (c < 128) v = outf[n * 128 + c] / fmaxf((float)rowcnt[n], 1.f);
    else v = incf[n * 128 + c - 128] / fmaxf((float)colcnt[n], 1.f);
    cat2[i] = v;
}

__global__ __launch_bounds__(256) void k_final(const float* __restrict__ un,
                                               const float* __restrict__ eatt,
                                               float* __restrict__ dst, int NC) {
    int i = blockIdx.x * 256 + threadIdx.x;
    if (i >= NC) return;
    dst[i] = fmaxf(un[i], 0.f) * eatt[i];
}

// ---------------------------------------------------------------- host orchestration

extern "C" void kernel_launch(void* const* d_in, const int* in_sizes, int n_in,
                              void* d_out, int out_size, void* d_ws, size_t ws_size,
                              hipStream_t stream) {
    const float* node_feature = (const float*)d_in[0];
    const float* edge_feature = (const float*)d_in[1];
    const int* edges = (const int*)d_in[2];
    const float* desc = (const float*)d_in[3];
    const float* qW = (const float*)d_in[4];
    const float* qB = (const float*)d_in[5];
    const float* kW = (const float*)d_in[6];
    const float* kB = (const float*)d_in[7];
    const float* vW = (const float*)d_in[8];
    const float* vB = (const float*)d_in[9];
    const float* dW1 = (const float*)d_in[10];
    const float* dB1 = (const float*)d_in[11];
    const float* dW2 = (const float*)d_in[12];
    const float* dB2 = (const float*)d_in[13];
    const float* eW1 = (const float*)d_in[14];
    const float* eB1 = (const float*)d_in[15];
    const float* eW2 = (const float*)d_in[16];
    const float* eB2 = (const float*)d_in[17];
    const float* attW1 = (const float*)d_in[18];
    const float* attB1 = (const float*)d_in[19];
    const float* attW2 = (const float*)d_in[20];
    const float* attB2 = (const float*)d_in[21];
    const float* nW1 = (const float*)d_in[22];
    const float* nB1 = (const float*)d_in[23];
    const float* nW2 = (const float*)d_in[24];
    const float* nB2 = (const float*)d_in[25];
    const float* aW = (const float*)d_in[26];
    const float* aB = (const float*)d_in[27];

    const int N = in_sizes[0] / 128;
    const int E = in_sizes[2] / 2;
    const int L = 2;
    const int* row = edges;
    const int* col = edges + E;

    char* wsp = (char*)d_ws;
    auto alloc = [&](size_t bytes) {
        char* p = wsp;
        wsp += (bytes + 255) & ~(size_t)255;
        return p;
    };
    unsigned* hashK = (unsigned*)alloc((size_t)HS * 4);
    int* hashV = (int*)alloc((size_t)HS * 4);
    int* ridx = (int*)alloc((size_t)E * 4);
    int* rowcnt = (int*)alloc((size_t)N * 4);
    int* colcnt = (int*)alloc((size_t)N * 4);
    float* xq = (float*)alloc((size_t)N * 128 * 4);
    float* xv = (float*)alloc((size_t)N * 128 * 4);
    float* xa = (float*)alloc((size_t)N * 384 * 4);
    float* xb = (float*)alloc((size_t)N * 384 * 4);
    float* kbuf = (float*)alloc((size_t)E * 128 * 4);
    float* efbuf = (float*)alloc((size_t)E * 128 * 4);
    float* dmbuf = (float*)alloc((size_t)E * 4);
    const int CH = 32000;
    float* h1c = (float*)alloc((size_t)CH * 384 * 4);
    unsigned* aggenc = (unsigned*)alloc((size_t)N * 128 * 4);
    float* ncat = (float*)alloc((size_t)N * 256 * 4);
    float* nh1 = (float*)alloc((size_t)N * 256 * 4);
    float* un = (float*)alloc((size_t)N * 128 * 4);
    float* outf = (float*)alloc((size_t)N * 128 * 4);
    float* incf = (float*)alloc((size_t)N * 128 * 4);
    float* cat2 = (float*)alloc((size_t)N * 256 * 4);
    float* eattb = (float*)alloc((size_t)N * 128 * 4);
    float* xbuf = (float*)alloc((size_t)N * 128 * 4);
    unsigned short* wt1_hi = (unsigned short*)alloc((size_t)384 * 256 * 2);
    unsigned short* wt1_lo = (unsigned short*)alloc((size_t)384 * 256 * 2);
    unsigned short* wt2_hi = (unsigned short*)alloc((size_t)128 * 384 * 2);
    unsigned short* wt2_lo = (unsigned short*)alloc((size_t)128 * 384 * 2);
    unsigned short* wtk_hi = (unsigned short*)alloc((size_t)128 * 128 * 2);
    unsigned short* wtk_lo = (unsigned short*)alloc((size_t)128 * 128 * 2);

    float* out_x = (float*)d_out;
    float* out_ef = out_x + (size_t)N * 128;
    float* out_prob = out_ef + (size_t)E * 128;

    k_init_static<<<(HS + 255) / 256, 256, 0, stream>>>(hashK, hashV, rowcnt, colcnt, N);
    k_hash_insert<<<(E + 255) / 256, 256, 0, stream>>>(row, col, hashK, hashV, N, E);
    k_hash_lookup<<<(E + 255) / 256, 256, 0, stream>>>(row, col, hashK, hashV, ridx, rowcnt, colcnt, N, E);

    for (int l = 0; l < L; ++l) {
        const float* x_cur = (l == 0) ? node_feature : xbuf;
        const float* ef_cur = (l == 0) ? edge_feature : efbuf;
        const bool last = (l == L - 1);

        const float* qW_l = qW + (size_t)l * 128 * 128;
        const float* qB_l = qB + (size_t)l * 128;
        const float* kW_l = kW + (size_t)l * 128 * 128;
        const float* kB_l = kB + (size_t)l * 128;
        const float* vW_l = vW + (size_t)l * 128 * 128;
        const float* vB_l = vB + (size_t)l * 128;
        const float* dW1_l = dW1 + (size_t)l * 128;
        const float* dB1_l = dB1 + (size_t)l * 32;
        const float* dW2_l = dW2 + (size_t)l * 32;
        const float* dB2_l = dB2 + (size_t)l * 1;
        const float* eW1_l = eW1 + (size_t)l * 512 * 384;
        const float* eB1_l = eB1 + (size_t)l * 384;
        const float* eW2_l = eW2 + (size_t)l * 384 * 128;
        const float* eB2_l = eB2 + (size_t)l * 128;
        const float* attW1_l = attW1 + (size_t)l * 32 * 32;
        const float* attB1_l = attB1 + (size_t)l * 32;
        const float* attW2_l = attW2 + (size_t)l * 16 * 32;
        const float* attB2_l = attB2 + (size_t)l * 16;
        const float* nW1_l = nW1 + (size_t)l * 256 * 256;
        const float* nB1_l = nB1 + (size_t)l * 256;
        const float* nW2_l = nW2 + (size_t)l * 256 * 128;
        const float* nB2_l = nB2 + (size_t)l * 128;
        const float* aW_l = aW + (size_t)l * 256 * 128;
        const float* aB_l = aB + (size_t)l * 128;

        // weight prep (transpose + bf16 split)
        k_prep_wt<<<(256 * 384 + 255) / 256, 256, 0, stream>>>(eW1_l + (size_t)128 * 384, wt1_hi, wt1_lo, 256, 384);
        k_prep_wt<<<(384 * 128 + 255) / 256, 256, 0, stream>>>(eW2_l, wt2_hi, wt2_lo, 384, 128);
        k_prep_wt<<<(128 * 128 + 255) / 256, 256, 0, stream>>>(kW_l, wtk_hi, wtk_lo, 128, 128);

        k_layer_init<<<(N * 128 + 255) / 256, 256, 0, stream>>>(aggenc, outf, incf, N * 128);

        // distance-gate MLP precompute (per edge)
        k_dm<<<(E + 255) / 256, 256, 0, stream>>>(desc, row, col, dW1_l, dB1_l, dW2_l, dB2_l, dmbuf, E);

        int gy_n = (N + 63) / 64;
        // per-node precomputes (fp32)
        k_gemm<0><<<dim3(2, gy_n), 256, 0, stream>>>(x_cur, qW_l, qB_l, xq, N, 128, 128, 128, 128, 128);
        k_gemm<0><<<dim3(2, gy_n), 256, 0, stream>>>(x_cur, vW_l, vB_l, xv, N, 128, 128, 128, 128, 128);
        k_gemm<0><<<dim3(6, gy_n), 256, 0, stream>>>(x_cur, eW1_l, nullptr, xa, N, 384, 128, 128, 384, 384);
        k_gemm<0><<<dim3(6, gy_n), 256, 0, stream>>>(x_cur, eW1_l + (size_t)384 * 384, nullptr, xb, N, 384, 128, 128, 384, 384);
        // per-edge k projection (MFMA)
        k_mfma_gemm<2, 4><<<dim3(1, (E + 127) / 128), 256, 0, stream>>>(
            ef_cur, nullptr, wtk_hi, wtk_lo, kB_l, nullptr, nullptr, nullptr, nullptr,
            kbuf, nullptr, nullptr, 0, E, 0);
        // attention + prob + segment-max (MFMA, 2 edges per wave-iteration)
        k_attn<<<2048, 256, 0, stream>>>(xq, kbuf, xv, row, col, attW1_l, attB1_l, attW2_l, attB2_l,
                                         dmbuf, out_prob + (size_t)l * E * 128, aggenc, E);
        // edge MLP in chunks (MFMA)
        for (int cb = 0; cb < E; cb += CH) {
            int mrows = (E - cb < CH) ? (E - cb) : CH;
            int gy = (mrows + 127) / 128;
            k_mfma_gemm<0, 8><<<dim3(3, gy), 256, 0, stream>>>(
                ef_cur, ridx, wt1_hi, wt1_lo, eB1_l, xa, xb, row, col,
                h1c, nullptr, nullptr, cb, mrows, 0);
            k_mfma_gemm<1, 12><<<dim3(1, gy), 256, 0, stream>>>(
                h1c, nullptr, wt2_hi, wt2_lo, eB2_l, nullptr, nullptr, row, col,
                last ? out_ef : efbuf, outf, incf, cb, mrows, last ? 0 : 1);
        }
        // node update
        k_ncat<<<(N * 256 + 255) / 256, 256, 0, stream>>>(x_cur, aggenc, ncat, N);
        k_gemm<1><<<dim3(4, gy_n), 256, 0, stream>>>(ncat, nW1_l, nB1_l, nh1, N, 256, 256, 256, 256, 256);
        k_gemm<0><<<dim3(2, gy_n), 256, 0, stream>>>(nh1, nW2_l, nB2_l, un, N, 128, 256, 256, 128, 128);
        k_cat2<<<(N * 256 + 255) / 256, 256, 0, stream>>>(outf, incf, rowcnt, colcnt, cat2, N);
        k_gemm<2><<<dim3(2, gy_n), 256, 0, stream>>>(cat2, aW_l, aB_l, eattb, N, 128, 256, 256, 128, 128);
        k_final<<<(N * 128 + 255) / 256, 256, 0, stream>>>(un, eattb, last ? out_x : xbuf, N * 128);
    }
}

// Round 4
// 1975.490 us; speedup vs baseline: 1.4471x; 1.1478x over previous
//
#include <hip/hip_runtime.h>
#include <math.h>

#define HS 524288
#define HSM (HS - 1)
#define ENC_NEGINF 0x007FFFFFu

__device__ __forceinline__ unsigned encf(float f) {
    unsigned b = __float_as_uint(f);
    return (b & 0x80000000u) ? ~b : (b | 0x80000000u);
}
__device__ __forceinline__ float decf(unsigned u) {
    return __uint_as_float((u & 0x80000000u) ? (u & 0x7FFFFFFFu) : ~u);
}

__device__ __forceinline__ unsigned short f2bf(float x) {
    unsigned u = __float_as_uint(x);
    unsigned r = u + 0x7FFFu + ((u >> 16) & 1u);
    return (unsigned short)(r >> 16);
}
__device__ __forceinline__ float bf2f(unsigned short h) {
    return __uint_as_float(((unsigned)h) << 16);
}

using bfrag = __attribute__((ext_vector_type(8))) short;
using ffrag = __attribute__((ext_vector_type(4))) float;

// split 8 fp32 into hi/lo bf16 fragments
__device__ __forceinline__ void split8(const float* f, bfrag& hi, bfrag& lo) {
#pragma unroll
    for (int j = 0; j < 8; ++j) {
        unsigned short h = f2bf(f[j]);
        hi[j] = (short)h;
        lo[j] = (short)f2bf(f[j] - bf2f(h));
    }
}

// ---------------------------------------------------------------- setup kernels

__global__ __launch_bounds__(256) void k_init_static(unsigned* hashK, int* hashV,
                                                     int* rowcnt, int* colcnt, int N) {
    int i = blockIdx.x * 256 + threadIdx.x;
    if (i < HS) { hashK[i] = 0xFFFFFFFFu; hashV[i] = 0x7FFFFFFF; }
    if (i < N) { rowcnt[i] = 0; colcnt[i] = 0; }
}

__global__ __launch_bounds__(256) void k_hash_insert(const int* __restrict__ row,
                                                     const int* __restrict__ col,
                                                     unsigned* hashK, int* hashV, int N, int E) {
    int e = blockIdx.x * 256 + threadIdx.x;
    if (e >= E) return;
    unsigned key = (unsigned)row[e] * (unsigned)N + (unsigned)col[e];
    unsigned h = (key * 2654435761u) >> 13; h &= HSM;
    while (true) {
        unsigned prev = atomicCAS(&hashK[h], 0xFFFFFFFFu, key);
        if (prev == 0xFFFFFFFFu || prev == key) { atomicMin(&hashV[h], e); break; }
        h = (h + 1) & HSM;
    }
}

__global__ __launch_bounds__(256) void k_hash_lookup(const int* __restrict__ row,
                                                     const int* __restrict__ col,
                                                     const unsigned* __restrict__ hashK,
                                                     const int* __restrict__ hashV,
                                                     int* __restrict__ ridx,
                                                     int* rowcnt, int* colcnt, int N, int E) {
    int e = blockIdx.x * 256 + threadIdx.x;
    if (e >= E) return;
    int r = row[e], c = col[e];
    unsigned rkey = (unsigned)c * (unsigned)N + (unsigned)r;
    unsigned h = (rkey * 2654435761u) >> 13; h &= HSM;
    int res = -1;
    while (true) {
        unsigned kk = hashK[h];
        if (kk == rkey) { res = hashV[h]; break; }
        if (kk == 0xFFFFFFFFu) break;
        h = (h + 1) & HSM;
    }
    ridx[e] = res;
    atomicAdd(&rowcnt[r], 1);
    atomicAdd(&colcnt[c], 1);
}

__global__ __launch_bounds__(256) void k_layer_init(unsigned* aggenc, float* outf, float* incf, int NC) {
    int i = blockIdx.x * 256 + threadIdx.x;
    if (i >= NC) return;
    aggenc[i] = ENC_NEGINF;
    outf[i] = 0.f;
    incf[i] = 0.f;
}

// Weight prep: src fp32 [K][Nn] row-major -> whi/wlo bf16 [Nn][K] (transposed + split)
__global__ __launch_bounds__(256) void k_prep_wt(const float* __restrict__ src,
                                                 unsigned short* __restrict__ whi,
                                                 unsigned short* __restrict__ wlo,
                                                 int K, int Nn) {
    int idx = blockIdx.x * 256 + threadIdx.x;
    if (idx >= K * Nn) return;
    int k = idx / Nn, n = idx - k * Nn;
    float v = src[idx];
    unsigned short h = f2bf(v);
    float hf = bf2f(h);
    unsigned short l = f2bf(v - hf);
    whi[(size_t)n * K + k] = h;
    wlo[(size_t)n * K + k] = l;
}

// Activation pre-split: fp32 -> hi/lo bf16 arrays (vectorized by 4)
__global__ __launch_bounds__(256) void k_presplit(const float* __restrict__ src,
                                                  unsigned short* __restrict__ hi,
                                                  unsigned short* __restrict__ lo, int n4) {
    int i = blockIdx.x * 256 + threadIdx.x;
    if (i >= n4) return;
    float4 f = ((const float4*)src)[i];
    ushort4 h, l;
    h.x = f2bf(f.x); l.x = f2bf(f.x - bf2f(h.x));
    h.y = f2bf(f.y); l.y = f2bf(f.y - bf2f(h.y));
    h.z = f2bf(f.z); l.z = f2bf(f.z - bf2f(h.z));
    h.w = f2bf(f.w); l.w = f2bf(f.w - bf2f(h.w));
    ((ushort4*)hi)[i] = h;
    ((ushort4*)lo)[i] = l;
}

// ---------------------------------------------------------------- generic fp32 GEMM (node-side)
template <int ACT>
__global__ __launch_bounds__(256) void k_gemm(const float* __restrict__ A,
                                              const float* __restrict__ B,
                                              const float* __restrict__ bias,
                                              float* __restrict__ C,
                                              int M, int Nd, int K, int lda, int ldb, int ldc) {
    __shared__ float As[16][64];
    __shared__ float Bs[16][64];
    const int tid = threadIdx.x;
    const int bm = blockIdx.y * 64, bn = blockIdx.x * 64;
    const int tx = tid & 15, ty = tid >> 4;
    const int mload = tid >> 2, k4 = (tid & 3) << 2;
    const int kload = tid >> 4, n4 = (tid & 15) << 2;
    float acc[4][4] = {};
    const int gmload = bm + mload;
    const bool avalid = (gmload < M);
    const float* aptr = A + (size_t)(avalid ? gmload : (M - 1)) * lda + k4;
    const float* bptr = B + (size_t)kload * ldb + bn + n4;
    for (int kb = 0; kb < K; kb += 16) {
        float4 av = avalid ? *(const float4*)(aptr + kb) : make_float4(0.f, 0.f, 0.f, 0.f);
        As[k4 + 0][mload] = av.x; As[k4 + 1][mload] = av.y;
        As[k4 + 2][mload] = av.z; As[k4 + 3][mload] = av.w;
        *(float4*)&Bs[kload][n4] = *(const float4*)(bptr + (size_t)kb * ldb);
        __syncthreads();
#pragma unroll
        for (int k = 0; k < 16; ++k) {
            float4 a = *(const float4*)&As[k][ty << 2];
            float4 b = *(const float4*)&Bs[k][tx << 2];
            acc[0][0] += a.x * b.x; acc[0][1] += a.x * b.y; acc[0][2] += a.x * b.z; acc[0][3] += a.x * b.w;
            acc[1][0] += a.y * b.x; acc[1][1] += a.y * b.y; acc[1][2] += a.y * b.z; acc[1][3] += a.y * b.w;
            acc[2][0] += a.z * b.x; acc[2][1] += a.z * b.y; acc[2][2] += a.z * b.z; acc[2][3] += a.z * b.w;
            acc[3][0] += a.w * b.x; acc[3][1] += a.w * b.y; acc[3][2] += a.w * b.z; acc[3][3] += a.w * b.w;
        }
        __syncthreads();
    }
#pragma unroll
    for (int i = 0; i < 4; ++i) {
        int gm = bm + (ty << 2) + i;
        if (gm >= M) continue;
        float* crow = C + (size_t)gm * ldc;
#pragma unroll
        for (int j = 0; j < 4; ++j) {
            int gn = bn + (tx << 2) + j;
            float v = acc[i][j];
            if (bias) v += bias[gn];
            if (ACT == 1) v = fmaxf(v, 0.f);
            if (ACT == 2) v = 1.f / (1.f + __expf(-v));
            crow[gn] = v;
        }
    }
}

// ---------------------------------------------------------------- MFMA split-bf16 GEMM
// 128x128 tile, BK=32, 4 waves (2x2), each wave 64x64 via 16x16x32 bf16 MFMA.
// 3-term split: D += Ahi*Bhi + Alo*Bhi + Ahi*Blo  (error ~2^-17, fp32-equivalent).
// A is PRE-SPLIT bf16 hi/lo in memory (staging = pure uint4 copy, no VALU conversion).
// NOTE: the per-thread k-half offset kh is baked into BOTH A and B source pointers
// (round-3 bug: kh was missing from A side -> upper K-half duplicated lower half).
// MODE 0 (H1): A = [ef[e] | ef[ridx[e]]], K=256, epilogue relu(acc+eB1+xa[row]+xb[col])
//              -> written SPLIT to h1hi/h1lo [E][384]
// MODE 1 (U):  A = h1 (stride 384), K=384, epilogue v=acc+eB2 -> atomics outf/incf;
//              rawOut ? fp32 out_ef : split relu(v) -> efhi/eflo (next layer input)
// MODE 2 (K):  A = ef, K=128, epilogue acc+kB -> kbuf (fp32)

#define LDP 40   // LDS row pitch in shorts (BK 32 + 8): 80B rows, 16B-aligned, ~2-way banks

template <int MODE, int KSTEPS>
__global__ __launch_bounds__(256) void k_mfma_gemm(const unsigned short* __restrict__ Ahi_s,
                                                   const unsigned short* __restrict__ Alo_s,
                                                   const int* __restrict__ ridx,
                                                   const unsigned short* __restrict__ Bhi,
                                                   const unsigned short* __restrict__ Blo,
                                                   const float* __restrict__ bias,
                                                   const float* __restrict__ xa,
                                                   const float* __restrict__ xb,
                                                   const int* __restrict__ rowArr,
                                                   const int* __restrict__ colArr,
                                                   float* __restrict__ outC,
                                                   unsigned short* __restrict__ outHi,
                                                   unsigned short* __restrict__ outLo,
                                                   float* __restrict__ outf,
                                                   float* __restrict__ incf,
                                                   int Mrows, int rawOut) {
    constexpr int K = KSTEPS * 32;
    constexpr int AST = (MODE == 1) ? 384 : 128;   // A row stride in shorts
    __shared__ unsigned short Ah[128 * LDP];
    __shared__ unsigned short Al[128 * LDP];
    __shared__ unsigned short Bh[128 * LDP];
    __shared__ unsigned short Bl[128 * LDP];

    const int tid = threadIdx.x;
    const int bm = blockIdx.y * 128;
    const int bx = blockIdx.x;

    // staging assignment: thread -> row sr = tid>>1, k-half kh = (tid&1)*16 (shorts)
    const int sr = tid >> 1;
    const int kh = (tid & 1) * 16;

    // kh baked into all four A source pointers (and B below)
    const unsigned short *p0h, *p0l, *p1h = nullptr, *p1l = nullptr;
    {
        int rc = min(bm + sr, Mrows - 1);
        p0h = Ahi_s + (size_t)rc * AST + kh;
        p0l = Alo_s + (size_t)rc * AST + kh;
        if (MODE == 0) {
            int rv = ridx[rc];
            if (rv >= 0) { p1h = Ahi_s + (size_t)rv * 128 + kh; p1l = Alo_s + (size_t)rv * 128 + kh; }
        }
    }
    const unsigned short* bhp = Bhi + (size_t)(bx * 128 + sr) * K + kh;
    const unsigned short* blp = Blo + (size_t)(bx * 128 + sr) * K + kh;

    const int wid = tid >> 6;
    const int lane = tid & 63;
    const int wr0 = (wid >> 1) * 64;
    const int wc0 = (wid & 1) * 64;
    const int lm = lane & 15;
    const int lk = (lane >> 4) * 8;

    ffrag acc[4][4];
#pragma unroll
    for (int i = 0; i < 4; ++i)
#pragma unroll
        for (int j = 0; j < 4; ++j)
            acc[i][j] = (ffrag){0.f, 0.f, 0.f, 0.f};

    unsigned short* AhW = &Ah[sr * LDP + kh];
    unsigned short* AlW = &Al[sr * LDP + kh];
    unsigned short* BhW = &Bh[sr * LDP + kh];
    unsigned short* BlW = &Bl[sr * LDP + kh];

    for (int ks = 0; ks < KSTEPS; ++ks) {
        const int kb = ks * 32;
        // ---- stage A (pure copy of pre-split shorts)
        const unsigned short* sh = p0h + kb;
        const unsigned short* sl = p0l + kb;
        if (MODE == 0 && kb >= 128) {
            sh = p1h ? p1h + (kb - 128) : nullptr;
            sl = p1l ? p1l + (kb - 128) : nullptr;
        }
        {
            const uint4 z = (uint4){0u, 0u, 0u, 0u};
            uint4 h0 = sh ? *(const uint4*)(sh) : z;
            uint4 h1 = sh ? *(const uint4*)(sh + 8) : z;
            uint4 l0 = sh ? *(const uint4*)(sl) : z;
            uint4 l1 = sh ? *(const uint4*)(sl + 8) : z;
            *(uint4*)(AhW) = h0; *(uint4*)(AhW + 8) = h1;
            *(uint4*)(AlW) = l0; *(uint4*)(AlW + 8) = l1;
        }
        // ---- stage B (pre-split bf16, straight copy)
        {
            uint4 b0 = *(const uint4*)(bhp + kb);
            uint4 b1 = *(const uint4*)(bhp + kb + 8);
            uint4 c0 = *(const uint4*)(blp + kb);
            uint4 c1 = *(const uint4*)(blp + kb + 8);
            *(uint4*)(BhW) = b0; *(uint4*)(BhW + 8) = b1;
            *(uint4*)(BlW) = c0; *(uint4*)(BlW + 8) = c1;
        }
        __syncthreads();
        // ---- fragments + MFMA
        bfrag a_h[4], a_l[4], b_h[4], b_l[4];
#pragma unroll
        for (int mt = 0; mt < 4; ++mt) {
            int base = (wr0 + mt * 16 + lm) * LDP + lk;
            a_h[mt] = *(const bfrag*)&Ah[base];
            a_l[mt] = *(const bfrag*)&Al[base];
        }
#pragma unroll
        for (int nt = 0; nt < 4; ++nt) {
            int base = (wc0 + nt * 16 + lm) * LDP + lk;
            b_h[nt] = *(const bfrag*)&Bh[base];
            b_l[nt] = *(const bfrag*)&Bl[base];
        }
#pragma unroll
        for (int mt = 0; mt < 4; ++mt)
#pragma unroll
            for (int nt = 0; nt < 4; ++nt) {
                acc[mt][nt] = __builtin_amdgcn_mfma_f32_16x16x32_bf16(a_h[mt], b_h[nt], acc[mt][nt], 0, 0, 0);
                acc[mt][nt] = __builtin_amdgcn_mfma_f32_16x16x32_bf16(a_l[mt], b_h[nt], acc[mt][nt], 0, 0, 0);
                acc[mt][nt] = __builtin_amdgcn_mfma_f32_16x16x32_bf16(a_h[mt], b_l[nt], acc[mt][nt], 0, 0, 0);
            }
        __syncthreads();
    }

    // ---- epilogue. C/D layout: col = lane&15, row = (lane>>4)*4 + reg.
    float bv[4];
#pragma unroll
    for (int nt = 0; nt < 4; ++nt) bv[nt] = bias[bx * 128 + wc0 + nt * 16 + lm];

#pragma unroll
    for (int mt = 0; mt < 4; ++mt) {
#pragma unroll
        for (int i = 0; i < 4; ++i) {
            int grow = bm + wr0 + mt * 16 + (lane >> 4) * 4 + i;
            if (grow >= Mrows) continue;
            if (MODE == 0) {
                size_t re = (size_t)rowArr[grow] * 384;
                size_t ce = (size_t)colArr[grow] * 384;
                unsigned short* hr = outHi + (size_t)grow * 384;
                unsigned short* lr = outLo + (size_t)grow * 384;
#pragma unroll
                for (int nt = 0; nt < 4; ++nt) {
                    int gcol = bx * 128 + wc0 + nt * 16 + lm;
                    float v = acc[mt][nt][i] + bv[nt] + xa[re + gcol] + xb[ce + gcol];
                    v = fmaxf(v, 0.f);
                    unsigned short hb = f2bf(v);
                    hr[gcol] = hb;
                    lr[gcol] = f2bf(v - bf2f(hb));
                }
            } else if (MODE == 1) {
                size_t re = (size_t)rowArr[grow] * 128;
                size_t ce = (size_t)colArr[grow] * 128;
#pragma unroll
                for (int nt = 0; nt < 4; ++nt) {
                    int gcol = wc0 + nt * 16 + lm;
                    float v = acc[mt][nt][i] + bv[nt];
                    atomicAdd(&outf[re + gcol], v);
                    atomicAdd(&incf[ce + gcol], v);
                    if (rawOut) {
                        outC[(size_t)grow * 128 + gcol] = v;
                    } else {
                        float rv = fmaxf(v, 0.f);
                        unsigned short hb = f2bf(rv);
                        outHi[(size_t)grow * 128 + gcol] = hb;
                        outLo[(size_t)grow * 128 + gcol] = f2bf(rv - bf2f(hb));
                    }
                }
            } else {
                float* crow = outC + (size_t)grow * 128;
#pragma unroll
                for (int nt = 0; nt < 4; ++nt) {
                    int gcol = wc0 + nt * 16 + lm;
                    crow[gcol] = acc[mt][nt][i] + bv[nt];
                }
            }
        }
    }
}

// ---------------------------------------------------------------- distance-gate MLP precompute

__global__ __launch_bounds__(256) void k_dm(const float* __restrict__ desc,
                                            const int* __restrict__ row,
                                            const int* __restrict__ col,
                                            const float* __restrict__ dW1,
                                            const float* __restrict__ dB1,
                                            const float* __restrict__ dW2,
                                            const float* __restrict__ dB2,
                                            float* __restrict__ dmbuf, int E) {
    __shared__ float sw[128];
    __shared__ float sb[32];
    __shared__ float sv[32];
    for (int i = threadIdx.x; i < 128; i += 256) sw[i] = dW1[i];
    if (threadIdx.x < 32) { sb[threadIdx.x] = dB1[threadIdx.x]; sv[threadIdx.x] = dW2[threadIdx.x]; }
    __syncthreads();
    const float db2v = dB2[0];
    for (int e = blockIdx.x * 256 + threadIdx.x; e < E; e += gridDim.x * 256) {
        int r = row[e], c = col[e];
        float dx = desc[r * 8 + 0] - desc[c * 8 + 0];
        float dy = desc[r * 8 + 1] - desc[c * 8 + 1];
        float dz = desc[r * 8 + 2] - desc[c * 8 + 2];
        float dist = sqrtf(dx * dx + dy * dy + dz * dz);
        float acc = db2v;
#pragma unroll
        for (int j = 0; j < 32; ++j) {
            float t = sb[j] + dx * sw[j] + dy * sw[32 + j] + dz * sw[64 + j] + dist * sw[96 + j];
            acc += fmaxf(t, 0.f) * sv[j];
        }
        dmbuf[e] = 1.f / (1.f + __expf(-acc));
    }
}

// ---------------------------------------------------------------- attention kernel (MFMA)
// 2 edges per wave-iteration = 16 (edge,head) rows per 16x16x32 MFMA tile.

__global__ __launch_bounds__(256) void k_attn(const float* __restrict__ xq,
                                              const float* __restrict__ kbuf,
                                              const float* __restrict__ xv,
                                              const int* __restrict__ row,
                                              const int* __restrict__ col,
                                              const float* __restrict__ attW1,
                                              const float* __restrict__ attB1,
                                              const float* __restrict__ attW2,
                                              const float* __restrict__ attB2,
                                              const float* __restrict__ dmbuf,
                                              float* __restrict__ prob_out,
                                              unsigned* __restrict__ aggenc, int E) {
    __shared__ float sh1[4][16 * 36];   // per-wave h1 bounce (2304 B each)

    const int tid = threadIdx.x;
    const int wv = tid >> 6;
    const int lane = tid & 63;
    const int lm = lane & 15;       // eh index within tile (edge pair: lm>>3, head: lm&7)
    const int lk = lane >> 4;       // k-group
    float* bounce = sh1[wv];
    const int swz = (lm & 3) << 1;  // XOR chunk swizzle (even -> preserves pair adjacency)

    // ---- resident weight fragments (A-frag layout: lane holds W[row=lm(+t*16)][k=lk*8+j])
    bfrag w1h[2], w1l[2], w2h, w2l;
    {
        float tmp[8];
#pragma unroll
        for (int t = 0; t < 2; ++t) {
            const float* p = attW1 + (size_t)(t * 16 + lm) * 32 + lk * 8;
            *(float4*)&tmp[0] = *(const float4*)p;
            *(float4*)&tmp[4] = *(const float4*)(p + 4);
            split8(tmp, w1h[t], w1l[t]);
        }
        const float* p = attW2 + (size_t)lm * 32 + lk * 8;
        *(float4*)&tmp[0] = *(const float4*)p;
        *(float4*)&tmp[4] = *(const float4*)(p + 4);
        split8(tmp, w2h, w2l);
    }
    // biases: D rows are o = t*16 + lk*4 + r
    const float4 b1v0 = *(const float4*)(attB1 + lk * 4);
    const float4 b1v1 = *(const float4*)(attB1 + 16 + lk * 4);
    const float4 b2v = *(const float4*)(attB2 + lk * 4);

    const int gw = (blockIdx.x * 256 + tid) >> 6;
    const int nw = (gridDim.x * 256) >> 6;
    const int ngrp = (E + 1) >> 1;

    for (int g = gw; g < ngrp; g += nw) {
        const int e0 = g * 2;
        const int eL = e0 + (lm >> 3);          // this lane's edge
        const int ev = min(eL, E - 1);
        const int hd = lm & 7;
        const int rn = row[ev], cn = col[ev];

        // ---- gather B-frag of h^T: lane needs h[eh=lm][c=lk*8+j]
        float hf[8];
        {
            const float* base = (lk < 2)
                ? (xq + (size_t)rn * 128 + hd + lk * 64)
                : (kbuf + (size_t)ev * 128 + hd + (lk - 2) * 64);
#pragma unroll
            for (int j = 0; j < 8; ++j) hf[j] = base[j * 8];
        }
        bfrag hh, hl;
        split8(hf, hh, hl);

        // ---- matvec1: h1 = relu(W1 h + b1), accumulator pre-loaded with bias
        ffrag d0 = (ffrag){b1v0.x, b1v0.y, b1v0.z, b1v0.w};
        ffrag d1 = (ffrag){b1v1.x, b1v1.y, b1v1.z, b1v1.w};
        d0 = __builtin_amdgcn_mfma_f32_16x16x32_bf16(w1h[0], hh, d0, 0, 0, 0);
        d1 = __builtin_amdgcn_mfma_f32_16x16x32_bf16(w1h[1], hh, d1, 0, 0, 0);
        d0 = __builtin_amdgcn_mfma_f32_16x16x32_bf16(w1l[0], hh, d0, 0, 0, 0);
        d1 = __builtin_amdgcn_mfma_f32_16x16x32_bf16(w1l[1], hh, d1, 0, 0, 0);
        d0 = __builtin_amdgcn_mfma_f32_16x16x32_bf16(w1h[0], hl, d0, 0, 0, 0);
        d1 = __builtin_amdgcn_mfma_f32_16x16x32_bf16(w1h[1], hl, d1, 0, 0, 0);
#pragma unroll
        for (int r = 0; r < 4; ++r) { d0[r] = fmaxf(d0[r], 0.f); d1[r] = fmaxf(d1[r], 0.f); }

        // ---- LDS bounce: transpose h1 into B-fragment layout (swizzled chunks)
        *(float4*)&bounce[lm * 36 + ((lk) ^ swz) * 4] = (float4){d0[0], d0[1], d0[2], d0[3]};
        *(float4*)&bounce[lm * 36 + ((4 + lk) ^ swz) * 4] = (float4){d1[0], d1[1], d1[2], d1[3]};
        __builtin_amdgcn_wave_barrier();
        float h1f[8];
        *(float4*)&h1f[0] = *(const float4*)&bounce[lm * 36 + ((2 * lk) ^ swz) * 4];
        *(float4*)&h1f[4] = *(const float4*)&bounce[lm * 36 + ((2 * lk + 1) ^ swz) * 4];
        __builtin_amdgcn_wave_barrier();
        bfrag h1h, h1l;
        split8(h1f, h1h, h1l);

        // ---- matvec2: att = W2 h1 + b2
        ffrag a = (ffrag){b2v.x, b2v.y, b2v.z, b2v.w};
        a = __builtin_amdgcn_mfma_f32_16x16x32_bf16(w2h, h1h, a, 0, 0, 0);
        a = __builtin_amdgcn_mfma_f32_16x16x32_bf16(w2l, h1h, a, 0, 0, 0);
        a = __builtin_amdgcn_mfma_f32_16x16x32_bf16(w2h, h1l, a, 0, 0, 0);

        // ---- scale + softmax over o2 (rows; lanes lm,lm+16,lm+32,lm+48 hold one eh col)
        const float sc = dmbuf[ev] * 0.25f;
        float t0 = a[0] * sc, t1 = a[1] * sc, t2 = a[2] * sc, t3 = a[3] * sc;
        float mx = fmaxf(fmaxf(t0, t1), fmaxf(t2, t3));
        mx = fmaxf(mx, __shfl_xor(mx, 16, 64));
        mx = fmaxf(mx, __shfl_xor(mx, 32, 64));
        float x0 = __expf(t0 - mx), x1 = __expf(t1 - mx);
        float x2 = __expf(t2 - mx), x3 = __expf(t3 - mx);
        float s = x0 + x1 + x2 + x3;
        s += __shfl_xor(s, 16, 64);
        s += __shfl_xor(s, 32, 64);
        const float inv = 1.f / s;
        x0 *= inv; x1 *= inv; x2 *= inv; x3 *= inv;

        // ---- outputs: prob + segment-max(prob*v).  o2 = lk*4 + r
        if (eL < E) {
            const int ob = lk * 4;
            float* pr = prob_out + (size_t)eL * 128 + hd;
            const float* vp = xv + (size_t)cn * 128 + hd;
            unsigned* ab = aggenc + (size_t)rn * 128 + hd;
            pr[(ob + 0) * 8] = x0;
            pr[(ob + 1) * 8] = x1;
            pr[(ob + 2) * 8] = x2;
            pr[(ob + 3) * 8] = x3;
            atomicMax(&ab[(ob + 0) * 8], encf(x0 * vp[(ob + 0) * 8]));
            atomicMax(&ab[(ob + 1) * 8], encf(x1 * vp[(ob + 1) * 8]));
            atomicMax(&ab[(ob + 2) * 8], encf(x2 * vp[(ob + 2) * 8]));
            atomicMax(&ab[(ob + 3) * 8], encf(x3 * vp[(ob + 3) * 8]));
        }
    }
}

// ---------------------------------------------------------------- small elementwise kernels

__global__ __launch_bounds__(256) void k_ncat(const float* __restrict__ x,
                                              const unsigned* __restrict__ aggenc,
                                              float* __restrict__ ncat, int N) {
    int i = blockIdx.x * 256 + threadIdx.x;
    if (i >= N * 256) return;
    int n = i >> 8, c = i & 255;
    float v;
    if (c < 128) v = x[n * 128 + c];
    else {
        unsigned u = aggenc[n * 128 + c - 128];
        v = (u == ENC_NEGINF) ? 0.f : decf(u);
    }
    ncat[i] = v;
}

__global__ __launch_bounds__(256) void k_cat2(const float* __restrict__ outf,
                                              const float* __restrict__ incf,
                                              const int* __restrict__ rowcnt,
                                              const int* __restrict__ colcnt,
                                              float* __restrict__ cat2, int N) {
    int i = blockIdx.x * 256 + threadIdx.x;
    if (i >= N * 256) return;
    int n = i >> 8, c = i & 255;
    float v;
    if (c < 128) v = outf[n * 128 + c] / fmaxf((float)rowcnt[n], 1.f);
    else v = incf[n * 128 + c - 128] / fmaxf((float)colcnt[n], 1.f);
    cat2[i] = v;
}

__global__ __launch_bounds__(256) void k_final(const float* __restrict__ un,
                                               const float* __restrict__ eatt,
                                               float* __restrict__ dst, int NC) {
    int i = blockIdx.x * 256 + threadIdx.x;
    if (i >= NC) return;
    dst[i] = fmaxf(un[i], 0.f) * eatt[i];
}

// ---------------------------------------------------------------- host orchestration

extern "C" void kernel_launch(void* const* d_in, const int* in_sizes, int n_in,
                              void* d_out, int out_size, void* d_ws, size_t ws_size,
                              hipStream_t stream) {
    const float* node_feature = (const float*)d_in[0];
    const float* edge_feature = (const float*)d_in[1];
    const int* edges = (const int*)d_in[2];
    const float* desc = (const float*)d_in[3];
    const float* qW = (const float*)d_in[4];
    const float* qB = (const float*)d_in[5];
    const float* kW = (const float*)d_in[6];
    const float* kB = (const float*)d_in[7];
    const float* vW = (const float*)d_in[8];
    const float* vB = (const float*)d_in[9];
    const float* dW1 = (const float*)d_in[10];
    const float* dB1 = (const float*)d_in[11];
    const float* dW2 = (const float*)d_in[12];
    const float* dB2 = (const float*)d_in[13];
    const float* eW1 = (const float*)d_in[14];
    const float* eB1 = (const float*)d_in[15];
    const float* eW2 = (const float*)d_in[16];
    const float* eB2 = (const float*)d_in[17];
    const float* attW1 = (const float*)d_in[18];
    const float* attB1 = (const float*)d_in[19];
    const float* attW2 = (const float*)d_in[20];
    const float* attB2 = (const float*)d_in[21];
    const float* nW1 = (const float*)d_in[22];
    const float* nB1 = (const float*)d_in[23];
    const float* nW2 = (const float*)d_in[24];
    const float* nB2 = (const float*)d_in[25];
    const float* aW = (const float*)d_in[26];
    const float* aB = (const float*)d_in[27];

    const int N = in_sizes[0] / 128;
    const int E = in_sizes[2] / 2;
    const int L = 2;
    const int* row = edges;
    const int* col = edges + E;

    char* wsp = (char*)d_ws;
    auto alloc = [&](size_t bytes) {
        char* p = wsp;
        wsp += (bytes + 255) & ~(size_t)255;
        return p;
    };
    unsigned* hashK = (unsigned*)alloc((size_t)HS * 4);
    int* hashV = (int*)alloc((size_t)HS * 4);
    int* ridx = (int*)alloc((size_t)E * 4);
    int* rowcnt = (int*)alloc((size_t)N * 4);
    int* colcnt = (int*)alloc((size_t)N * 4);
    float* xq = (float*)alloc((size_t)N * 128 * 4);
    float* xv = (float*)alloc((size_t)N * 128 * 4);
    float* xa = (float*)alloc((size_t)N * 384 * 4);
    float* xb = (float*)alloc((size_t)N * 384 * 4);
    float* kbuf = (float*)alloc((size_t)E * 128 * 4);
    float* dmbuf = (float*)alloc((size_t)E * 4);
    unsigned short* efA_hi = (unsigned short*)alloc((size_t)E * 128 * 2);
    unsigned short* efA_lo = (unsigned short*)alloc((size_t)E * 128 * 2);
    unsigned short* efB_hi = (unsigned short*)alloc((size_t)E * 128 * 2);
    unsigned short* efB_lo = (unsigned short*)alloc((size_t)E * 128 * 2);
    unsigned short* h1hi = (unsigned short*)alloc((size_t)E * 384 * 2);
    unsigned short* h1lo = (unsigned short*)alloc((size_t)E * 384 * 2);
    unsigned* aggenc = (unsigned*)alloc((size_t)N * 128 * 4);
    float* ncat = (float*)alloc((size_t)N * 256 * 4);
    float* nh1 = (float*)alloc((size_t)N * 256 * 4);
    float* un = (float*)alloc((size_t)N * 128 * 4);
    float* outf = (float*)alloc((size_t)N * 128 * 4);
    float* incf = (float*)alloc((size_t)N * 128 * 4);
    float* cat2 = (float*)alloc((size_t)N * 256 * 4);
    float* eattb = (float*)alloc((size_t)N * 128 * 4);
    float* xbuf = (float*)alloc((size_t)N * 128 * 4);
    unsigned short* wt1_hi = (unsigned short*)alloc((size_t)384 * 256 * 2);
    unsigned short* wt1_lo = (unsigned short*)alloc((size_t)384 * 256 * 2);
    unsigned short* wt2_hi = (unsigned short*)alloc((size_t)128 * 384 * 2);
    unsigned short* wt2_lo = (unsigned short*)alloc((size_t)128 * 384 * 2);
    unsigned short* wtk_hi = (unsigned short*)alloc((size_t)128 * 128 * 2);
    unsigned short* wtk_lo = (unsigned short*)alloc((size_t)128 * 128 * 2);

    float* out_x = (float*)d_out;
    float* out_ef = out_x + (size_t)N * 128;
    float* out_prob = out_ef + (size_t)E * 128;

    k_init_static<<<(HS + 255) / 256, 256, 0, stream>>>(hashK, hashV, rowcnt, colcnt, N);
    k_hash_insert<<<(E + 255) / 256, 256, 0, stream>>>(row, col, hashK, hashV, N, E);
    k_hash_lookup<<<(E + 255) / 256, 256, 0, stream>>>(row, col, hashK, hashV, ridx, rowcnt, colcnt, N, E);
    // layer-0 edge features -> split bf16
    k_presplit<<<(E * 32 + 255) / 256, 256, 0, stream>>>(edge_feature, efA_hi, efA_lo, E * 32);

    const int gyE = (E + 127) / 128;

    for (int l = 0; l < L; ++l) {
        const float* x_cur = (l == 0) ? node_feature : xbuf;
        const unsigned short* efhi = (l == 0) ? efA_hi : efB_hi;
        const unsigned short* eflo = (l == 0) ? efA_lo : efB_lo;
        const bool last = (l == L - 1);

        const float* qW_l = qW + (size_t)l * 128 * 128;
        const float* qB_l = qB + (size_t)l * 128;
        const float* kW_l = kW + (size_t)l * 128 * 128;
        const float* kB_l = kB + (size_t)l * 128;
        const float* vW_l = vW + (size_t)l * 128 * 128;
        const float* vB_l = vB + (size_t)l * 128;
        const float* dW1_l = dW1 + (size_t)l * 128;
        const float* dB1_l = dB1 + (size_t)l * 32;
        const float* dW2_l = dW2 + (size_t)l * 32;
        const float* dB2_l = dB2 + (size_t)l * 1;
        const float* eW1_l = eW1 + (size_t)l * 512 * 384;
        const float* eB1_l = eB1 + (size_t)l * 384;
        const float* eW2_l = eW2 + (size_t)l * 384 * 128;
        const float* eB2_l = eB2 + (size_t)l * 128;
        const float* attW1_l = attW1 + (size_t)l * 32 * 32;
        const float* attB1_l = attB1 + (size_t)l * 32;
        const float* attW2_l = attW2 + (size_t)l * 16 * 32;
        const float* attB2_l = attB2 + (size_t)l * 16;
        const float* nW1_l = nW1 + (size_t)l * 256 * 256;
        const float* nB1_l = nB1 + (size_t)l * 256;
        const float* nW2_l = nW2 + (size_t)l * 256 * 128;
        const float* nB2_l = nB2 + (size_t)l * 128;
        const float* aW_l = aW + (size_t)l * 256 * 128;
        const float* aB_l = aB + (size_t)l * 128;

        // weight prep (transpose + bf16 split)
        k_prep_wt<<<(256 * 384 + 255) / 256, 256, 0, stream>>>(eW1_l + (size_t)128 * 384, wt1_hi, wt1_lo, 256, 384);
        k_prep_wt<<<(384 * 128 + 255) / 256, 256, 0, stream>>>(eW2_l, wt2_hi, wt2_lo, 384, 128);
        k_prep_wt<<<(128 * 128 + 255) / 256, 256, 0, stream>>>(kW_l, wtk_hi, wtk_lo, 128, 128);

        k_layer_init<<<(N * 128 + 255) / 256, 256, 0, stream>>>(aggenc, outf, incf, N * 128);

        // distance-gate MLP precompute (per edge)
        k_dm<<<(E + 255) / 256, 256, 0, stream>>>(desc, row, col, dW1_l, dB1_l, dW2_l, dB2_l, dmbuf, E);

        int gy_n = (N + 63) / 64;
        // per-node precomputes (fp32)
        k_gemm<0><<<dim3(2, gy_n), 256, 0, stream>>>(x_cur, qW_l, qB_l, xq, N, 128, 128, 128, 128, 128);
        k_gemm<0><<<dim3(2, gy_n), 256, 0, stream>>>(x_cur, vW_l, vB_l, xv, N, 128, 128, 128, 128, 128);
        k_gemm<0><<<dim3(6, gy_n), 256, 0, stream>>>(x_cur, eW1_l, nullptr, xa, N, 384, 128, 128, 384, 384);
        k_gemm<0><<<dim3(6, gy_n), 256, 0, stream>>>(x_cur, eW1_l + (size_t)384 * 384, nullptr, xb, N, 384, 128, 128, 384, 384);
        // per-edge k projection (MFMA)
        k_mfma_gemm<2, 4><<<dim3(1, gyE), 256, 0, stream>>>(
            efhi, eflo, nullptr, wtk_hi, wtk_lo, kB_l, nullptr, nullptr, nullptr, nullptr,
            kbuf, nullptr, nullptr, nullptr, nullptr, E, 0);
        // attention + prob + segment-max (MFMA, 2 edges per wave-iteration)
        k_attn<<<2048, 256, 0, stream>>>(xq, kbuf, xv, row, col, attW1_l, attB1_l, attW2_l, attB2_l,
                                         dmbuf, out_prob + (size_t)l * E * 128, aggenc, E);
        // edge MLP (MFMA, full E, no chunking)
        k_mfma_gemm<0, 8><<<dim3(3, gyE), 256, 0, stream>>>(
            efhi, eflo, ridx, wt1_hi, wt1_lo, eB1_l, xa, xb, row, col,
            nullptr, h1hi, h1lo, nullptr, nullptr, E, 0);
        k_mfma_gemm<1, 12><<<dim3(1, gyE), 256, 0, stream>>>(
            h1hi, h1lo, nullptr, wt2_hi, wt2_lo, eB2_l, nullptr, nullptr, row, col,
            out_ef, efB_hi, efB_lo, outf, incf, E, last ? 1 : 0);
        // node update
        k_ncat<<<(N * 256 + 255) / 256, 256, 0, stream>>>(x_cur, aggenc, ncat, N);
        k_gemm<1><<<dim3(4, gy_n), 256, 0, stream>>>(ncat, nW1_l, nB1_l, nh1, N, 256, 256, 256, 256, 256);
        k_gemm<0><<<dim3(2, gy_n), 256, 0, stream>>>(nh1, nW2_l, nB2_l, un, N, 128, 256, 256, 128, 128);
        k_cat2<<<(N * 256 + 255) / 256, 256, 0, stream>>>(outf, incf, rowcnt, colcnt, cat2, N);
        k_gemm<2><<<dim3(2, gy_n), 256, 0, stream>>>(cat2, aW_l, aB_l, eattb, N, 128, 256, 256, 128, 128);
        k_final<<<(N * 128 + 255) / 256, 256, 0, stream>>>(un, eattb, last ? out_x : xbuf, N * 128);
    }
}